// Round 12
// baseline (74.148 us; speedup 1.0000x reference)
//
#include <hip/hip_runtime.h>

// 2-layer tanh RNN, INP=6, HID=8, B=4096, T=512, + linear head to 1.
// R12 = R11 with the cvt_pkrtz type fix (bit_cast wrapper).
// Packed-f16-pair state + v_dot2_f32_f16: 8 lanes per element; lane q owns
// the PAIR (v[2q], v[2q+1]) of the fused state v = (h1[0..7] | h2[0..7])
// as one f16x2 VGPR. Per step: 7 DPPs gather all pairs; two output units
// per lane = 2x8 fdot2 (f32 accumulate); x path stays f32; one tanh pair;
// head = 2 ops + 2 quad-DPP adds, same-step. 8 elements/wave (512 waves).
// x staged via async global_load_lds (8-element interleave, conflict-free),
// double-buffered 64-step chunks, distance-2 register prefetch.

#define INP 6
#define HID 8
#define TT  512
#define CH  64                // steps per chunk
#define NCH (TT/CH)           // 8 chunks
#define EPW 8                 // elements per wave
#define CHF (CH*INP)          // 384 floats per element-chunk
#define BUFF (EPW*CHF)        // 3072 floats per LDS buffer

#define DPP_XOR1 0xB1   // quad_perm(1,0,3,2): lane ^ 1
#define DPP_XOR2 0x4E   // quad_perm(2,3,0,1): lane ^ 2
#define DPP_XOR3 0x1B   // quad_perm(3,2,1,0): lane ^ 3
#define DPP_HMIR 0x141  // row_half_mirror:    lane ^ 7 (within 8)

#define KSC 2.88539008177793f   // 2 / ln(2)

typedef _Float16 h2v __attribute__((ext_vector_type(2)));

template<int CTRL>
__device__ __forceinline__ int idpp(int v) {
    return __builtin_amdgcn_update_dpp(0, v, CTRL, 0xF, 0xF, true);
}
template<int CTRL>
__device__ __forceinline__ float fdpp(float v) {
    return __int_as_float(__builtin_amdgcn_update_dpp(
        0, __float_as_int(v), CTRL, 0xF, 0xF, true));
}
__device__ __forceinline__ h2v ash2(int v) { return __builtin_bit_cast(h2v, v); }

// pack two f32 -> f16x2 (RTZ), as a raw int (avoids __fp16/_Float16 clash)
__device__ __forceinline__ int pkrtz(float a, float b) {
    return __builtin_bit_cast(int, __builtin_amdgcn_cvt_pkrtz(a, b));
}

#if __has_builtin(__builtin_amdgcn_fdot2)
__device__ __forceinline__ float fdot2(h2v a, h2v b, float c) {
    return __builtin_amdgcn_fdot2(a, b, c, false);
}
#else
__device__ __forceinline__ float fdot2(h2v a, h2v b, float c) {
    return fmaf((float)a.x, (float)b.x, fmaf((float)a.y, (float)b.y, c));
}
#endif

// tanh on PRE-SCALED input (z = 2/ln2 * raw): 1 - 2/(exp2(z)+1)
__device__ __forceinline__ float ftanhs(float z) {
    float e = __builtin_amdgcn_exp2f(z);
    return fmaf(-2.0f, __builtin_amdgcn_rcpf(e + 1.0f), 1.0f);
}

// async global->LDS, 16B per lane, LDS dst = uniform base + lane*16
__device__ __forceinline__ void gl2lds16(const float* g, float* l) {
    __builtin_amdgcn_global_load_lds(
        (const __attribute__((address_space(1))) void*)g,
        (__attribute__((address_space(3))) void*)l, 16, 0, 0);
}

// 8-element interleaved LDS layout: float f of element e at float offset
// 32*(f>>2) + 4*e + (f&3); BASE includes el*4 + buffer. F0 = t_local*6, even.
#define PF3(dst, base, F0) do {                                                            \
    dst[0] = *reinterpret_cast<const float2*>((base) + ((((F0)+0)>>2)<<5) + (((F0)+0)&3)); \
    dst[1] = *reinterpret_cast<const float2*>((base) + ((((F0)+2)>>2)<<5) + (((F0)+2)&3)); \
    dst[2] = *reinterpret_cast<const float2*>((base) + ((((F0)+4)>>2)<<5) + (((F0)+4)&3)); \
} while (0)

// one fused step. Entry: vpi = packed pair of (h1(t)|h2(t-1)). Consumes
// x(t+1) in XC. Exit: vpi = pair of (h1(t+1)|h2(t)). Head o(t) captured
// same-step into oregA (s<4) / oregB (s>=4).
#define STEPC(S, XC)                                                \
  {                                                                 \
    int p1 = idpp<DPP_XOR1>(vpi);                                   \
    int p2 = idpp<DPP_XOR2>(vpi);                                   \
    int p3 = idpp<DPP_XOR3>(vpi);                                   \
    int p7 = idpp<DPP_HMIR>(vpi);                                   \
    int p4 = idpp<DPP_XOR3>(p7);                                    \
    int p5 = idpp<DPP_XOR2>(p7);                                    \
    int p6 = idpp<DPP_XOR1>(p7);                                    \
    float A0 = fmaf(wx0[0], XC[0].x, bias0);                        \
    float B0 = wx0[1] * XC[0].y;                                    \
    A0 = fmaf(wx0[2], XC[1].x, A0);                                 \
    B0 = fmaf(wx0[3], XC[1].y, B0);                                 \
    A0 = fmaf(wx0[4], XC[2].x, A0);                                 \
    B0 = fmaf(wx0[5], XC[2].y, B0);                                 \
    float A1 = fmaf(wx1[0], XC[0].x, bias1);                        \
    float B1 = wx1[1] * XC[0].y;                                    \
    A1 = fmaf(wx1[2], XC[1].x, A1);                                 \
    B1 = fmaf(wx1[3], XC[1].y, B1);                                 \
    A1 = fmaf(wx1[4], XC[2].x, A1);                                 \
    B1 = fmaf(wx1[5], XC[2].y, B1);                                 \
    A0 = fdot2(Wp0[0], ash2(vpi), A0);                              \
    B0 = fdot2(Wp0[1], ash2(p1), B0);                               \
    A0 = fdot2(Wp0[2], ash2(p2), A0);                               \
    B0 = fdot2(Wp0[3], ash2(p3), B0);                               \
    A0 = fdot2(Wp0[4], ash2(p4), A0);                               \
    B0 = fdot2(Wp0[5], ash2(p5), B0);                               \
    A0 = fdot2(Wp0[6], ash2(p6), A0);                               \
    B0 = fdot2(Wp0[7], ash2(p7), B0);                               \
    A1 = fdot2(Wp1[0], ash2(vpi), A1);                              \
    B1 = fdot2(Wp1[1], ash2(p1), B1);                               \
    A1 = fdot2(Wp1[2], ash2(p2), A1);                               \
    B1 = fdot2(Wp1[3], ash2(p3), B1);                               \
    A1 = fdot2(Wp1[4], ash2(p4), A1);                               \
    B1 = fdot2(Wp1[5], ash2(p5), B1);                               \
    A1 = fdot2(Wp1[6], ash2(p6), A1);                               \
    B1 = fdot2(Wp1[7], ash2(p7), B1);                               \
    float t0 = ftanhs(A0 + B0);                                     \
    float t1 = ftanhs(A1 + B1);                                     \
    float o = fmaf(wo1, t1, wo0 * t0);                              \
    o += fdpp<DPP_XOR1>(o);                                         \
    o += fdpp<DPP_XOR2>(o);                                         \
    if ((S) < 4) oregA = (q == 4 + (S)) ? o : oregA;                \
    else         oregB = (q == (S)) ? o : oregB;                    \
    vpi = pkrtz(t0, t1);                                            \
  }

// even step: issue the pair consumed two steps later, then compute
#define STEPE(S, CURB, NXTB, PB1, F1, PB2, F2, DO1, DO2)  \
  {                                                       \
    if (DO1) PF3(NXTB[0], PB1, F1);                       \
    if (DO2) PF3(NXTB[1], PB2, F2);                       \
    STEPC(S, CURB[0])                                     \
  }
#define STEPO(S, CURB) { STEPC(S, CURB[1]) }

#define STOREO(BASE)                                      \
  if (q >= 4) {                                           \
    ob[(BASE) + (q - 4)]     = oregA + bo;                \
    ob[(BASE) + 4 + (q - 4)] = oregB + bo;                \
  }

__global__ __launch_bounds__(64) void rnn_fused(
    const float* __restrict__ x,
    const float* __restrict__ Wih0, const float* __restrict__ Whh0,
    const float* __restrict__ bih0, const float* __restrict__ bhh0,
    const float* __restrict__ Wih1, const float* __restrict__ Whh1,
    const float* __restrict__ bih1, const float* __restrict__ bhh1,
    const float* __restrict__ Wout, const float* __restrict__ bout,
    float* __restrict__ out)
{
    __shared__ float lx[2 * BUFF];   // 24 KiB, double-buffered x chunks

    const int lane = threadIdx.x;        // 0..63
    const int q    = lane & 7;           // pair slot within element group
    const int el   = lane >> 3;          // element slot (0..7)
    const int ew0  = blockIdx.x * EPW;   // wave's first batch element
    const bool lo  = q < 4;              // lower: h1 pairs; upper: h2 pairs
    const int u0   = 2 * q;              // fused output indices (0..15)
    const int u1   = 2 * q + 1;

    // fused-state weight row: Wf(u,k) over v = (h1[0..7] | h2[0..7])
    //  u<8  (h1(t+1)[u]):  k<8 -> Whh0[u][k],      k>=8 -> 0
    //  u>=8 (h2(t)[u-8]):  k<8 -> Wih1[u-8][k],    k>=8 -> Whh1[u-8][k-8]
    auto wf = [&](int u, int k) -> float {
        if (u < 8) return (k < 8) ? Whh0[u * 8 + k] : 0.0f;
        int uu = u - 8;
        return (k < 8) ? Wih1[uu * 8 + k] : Whh1[uu * 8 + (k - 8)];
    };

    // packed pair-weights: Wp{0,1}[m] multiplies the gathered pair q^m
    h2v Wp0[8], Wp1[8];
#pragma unroll
    for (int m = 0; m < 8; ++m) {
        int p = q ^ m;
        Wp0[m] = h2v{(_Float16)(KSC * wf(u0, 2 * p)),
                     (_Float16)(KSC * wf(u0, 2 * p + 1))};
        Wp1[m] = h2v{(_Float16)(KSC * wf(u1, 2 * p)),
                     (_Float16)(KSC * wf(u1, 2 * p + 1))};
    }
    float wx0[6], wx1[6];
#pragma unroll
    for (int d = 0; d < 6; ++d) {
        wx0[d] = lo ? KSC * Wih0[u0 * INP + d] : 0.0f;
        wx1[d] = lo ? KSC * Wih0[u1 * INP + d] : 0.0f;
    }
    const float bias0 = KSC * (lo ? (bih0[u0] + bhh0[u0])
                                  : (bih1[u0 - 8] + bhh1[u0 - 8]));
    const float bias1 = KSC * (lo ? (bih0[u1] + bhh0[u1])
                                  : (bih1[u1 - 8] + bhh1[u1 - 8]));
    const float wo0 = lo ? 0.0f : Wout[2 * (q - 4)];
    const float wo1 = lo ? 0.0f : Wout[2 * (q - 4) + 1];
    const float bo  = bout[0];

    const float* xw = x + (size_t)ew0 * (TT * INP);
    float* ob = out + (size_t)(ew0 + el) * TT;

    // stage chunk c1 (8 elements x 384 floats) into buffer pn, interleaved:
    // LDS f4 slot S = q4*8 + e
    auto stage = [&](int c1, int pn) {
#pragma unroll
        for (int i = 0; i < 12; ++i) {
            const int e  = lane & 7;
            const int q4 = i * 8 + (lane >> 3);
            const float* src = xw + (size_t)e * (TT * INP) + c1 * CHF + q4 * 4;
            gl2lds16(src, &lx[pn * BUFF + i * 256]);
        }
    };

    int vpi = 0;                 // packed pair (v[2q], v[2q+1]) as f16x2
    float oregA = 0.0f, oregB = 0.0f;
    float2 xP[2][3], xQ[2][3];   // pair buffers: 2 timesteps each

    // ---- prologue: stage chunk 0; h1(0) pairs; prime xP = [x(1), x(2)] ----
    stage(0, 0);
    asm volatile("s_waitcnt vmcnt(0)" ::: "memory");
    __builtin_amdgcn_sched_barrier(0);
    {
        const float* rb = &lx[el * 4];
        float2 x0[3];
        PF3(x0, rb, 0);        // x(0)
        PF3(xP[0], rb, 6);     // x(1)
        PF3(xP[1], rb, 12);    // x(2)
        float z0 = bias0, z1 = bias1;
        z0 = fmaf(wx0[0], x0[0].x, z0); z1 = fmaf(wx1[0], x0[0].x, z1);
        z0 = fmaf(wx0[1], x0[0].y, z0); z1 = fmaf(wx1[1], x0[0].y, z1);
        z0 = fmaf(wx0[2], x0[1].x, z0); z1 = fmaf(wx1[2], x0[1].x, z1);
        z0 = fmaf(wx0[3], x0[1].y, z0); z1 = fmaf(wx1[3], x0[1].y, z1);
        z0 = fmaf(wx0[4], x0[2].x, z0); z1 = fmaf(wx1[4], x0[2].x, z1);
        z0 = fmaf(wx0[5], x0[2].y, z0); z1 = fmaf(wx1[5], x0[2].y, z1);
        int pk0 = pkrtz(ftanhs(z0), ftanhs(z1));
        vpi = lo ? pk0 : 0;    // h2(-1) = 0
    }

    for (int c = 0; c < NCH; ++c) {
        const int p = c & 1;
        if (c < NCH - 1) stage(c + 1, p ^ 1);          // ~64 steps of cover
        const float* rb = &lx[p * BUFF + el * 4];
        const float* nb = &lx[(p ^ 1) * BUFF + el * 4];

        for (int sb = 0; sb < 7; ++sb) {
            const float* rp = rb + sb * 384;           // body base
            STEPE(0, xP, xQ, rp, 18, rp, 24, true, true)
            STEPO(1, xP)
            STEPE(2, xQ, xP, rp, 30, rp, 36, true, true)
            STEPO(3, xQ)
            STEPE(4, xP, xQ, rp, 42, rp, 48, true, true)
            STEPO(5, xP)
            STEPE(6, xQ, xP, rp, 54, rp, 60, true, true)
            STEPO(7, xQ)
            STOREO(c * CH + sb * 8)
        }
        {   // body 7: steps 56..63, crossover into next chunk's buffer
            const float* rp = rb + 7 * 384;
            STEPE(0, xP, xQ, rp, 18, rp, 24, true, true)
            STEPO(1, xP)
            STEPE(2, xQ, xP, rp, 30, rp, 36, true, true)
            STEPO(3, xQ)
            if (c < NCH - 1) {
                // next chunk staged ~56 steps ago; drain once per chunk
                asm volatile("s_waitcnt vmcnt(0)" ::: "memory");
                __builtin_amdgcn_sched_barrier(0);
                STEPE(4, xP, xQ, rp, 42, nb, 0, true, true)  // local 63, next 0
                STEPO(5, xP)
                STEPE(6, xQ, xP, nb, 6, nb, 12, true, true)  // next 1, next 2
                STEPO(7, xQ)
            } else {
                // last chunk: x(512) doesn't exist; stale regs only feed
                // h1(512) (never used); h2(511)+head o(511) are exact
                STEPE(4, xP, xQ, rp, 42, rp, 0, true, false)
                STEPO(5, xP)
                STEPE(6, xQ, xP, rp, 0, rp, 0, false, false)
                STEPO(7, xQ)
            }
            STOREO(c * CH + 56)
        }
    }
}

extern "C" void kernel_launch(void* const* d_in, const int* in_sizes, int n_in,
                              void* d_out, int out_size, void* d_ws, size_t ws_size,
                              hipStream_t stream) {
    const float* x    = (const float*)d_in[0];
    const float* Wih0 = (const float*)d_in[1];
    const float* Whh0 = (const float*)d_in[2];
    const float* bih0 = (const float*)d_in[3];
    const float* bhh0 = (const float*)d_in[4];
    const float* Wih1 = (const float*)d_in[5];
    const float* Whh1 = (const float*)d_in[6];
    const float* bih1 = (const float*)d_in[7];
    const float* bhh1 = (const float*)d_in[8];
    const float* Wout = (const float*)d_in[9];
    const float* bout = (const float*)d_in[10];
    float* out = (float*)d_out;
    (void)d_ws; (void)ws_size; (void)in_sizes; (void)n_in; (void)out_size;

    // 4096 elements / 8 per wave = 512 single-wave blocks
    rnn_fused<<<512, 64, 0, stream>>>(x, Wih0, Whh0, bih0, bhh0,
                                      Wih1, Whh1, bih1, bhh1,
                                      Wout, bout, out);
}

// Round 14
// 70.850 us; speedup vs baseline: 1.0466x; 1.0466x over previous
//
#include <hip/hip_runtime.h>

// 2-layer tanh RNN, INP=6, HID=8, B=4096, T=512, + linear head to 1.
// R14 = R13 with (a) MFMA builtin gated on __HIP_DEVICE_COMPILE__ (host pass
// gets a parse-only dummy; R13 died in the HOST compile), (b) biasv computed
// from the QUANTIZED A entries so r=0.5 (tanh=0) is an exact fixed point.
// Design: 16 elements/wave; fused state (h1|h2) as 16x16 f16 matrix stored
// as r = 1/(exp2(KSC*z)+1) (tanh = 1-2r folded into A = -2*KSC*Wf).
// Per step:  D2 = mfma(A2, B2(x(t+1)), biasv)   [x-projection, 1-ahead]
//            D  = mfma(A,  B_state,    D2)      [whole fused update]
//            r  = rcp(exp2(D)+1) -> 2 pkrtz -> next B_state (lane-local)
// Head = 4 FMAs on h2 lanes + ds_swizzle xor16, deferred 2 steps.
// x staged via global_load_lds 64-step chunks (double buffer), ds_reads
// 2 steps ahead, 4-step units with static register ping-pong.

#define INP 6
#define TT  512
#define KSC 2.88539008177793f   // 2/ln(2)

typedef float  f32x4 __attribute__((ext_vector_type(4)));
typedef float  f32x2 __attribute__((ext_vector_type(2)));
typedef __fp16 f16x4 __attribute__((ext_vector_type(4)));
typedef unsigned int u32x2 __attribute__((ext_vector_type(2)));

#if defined(__HIP_DEVICE_COMPILE__)
  #if __has_builtin(__builtin_amdgcn_mfma_f32_16x16x16f16)
    #define MFMA16(A,B,C) __builtin_amdgcn_mfma_f32_16x16x16f16((A),(B),(C),0,0,0)
  #elif __has_builtin(__builtin_amdgcn_mfma_f32_16x16x16_f16)
    #define MFMA16(A,B,C) __builtin_amdgcn_mfma_f32_16x16x16_f16((A),(B),(C),0,0,0)
  #else
    #error "no 16x16x16 f16 MFMA on this target"
  #endif
#else
  #define MFMA16(A,B,C) (C)   // host pass: parse-only, never executed
#endif

__device__ __forceinline__ unsigned pkrtz(float a, float b) {
    return __builtin_bit_cast(unsigned, __builtin_amdgcn_cvt_pkrtz(a, b));
}
__device__ __forceinline__ f16x4 mkb(unsigned lo, unsigned hi) {
    u32x2 t; t.x = lo; t.y = hi;
    return __builtin_bit_cast(f16x4, t);
}
// lane l <-> l^16 exchange (BitMode: xor=16, and=0x1F)
__device__ __forceinline__ float swz16(float v) {
    return __int_as_float(__builtin_amdgcn_ds_swizzle(__float_as_int(v), 0x401F));
}
// async global->LDS, 16B per lane, LDS dst = uniform base + lane*16
__device__ __forceinline__ void gl2lds16(const float* g, float* l) {
    __builtin_amdgcn_global_load_lds(
        (const __attribute__((address_space(1))) void*)g,
        (__attribute__((address_space(3))) void*)l, 16, 0, 0);
}

__global__ __launch_bounds__(64) void rnn_mfma(
    const float* __restrict__ x,
    const float* __restrict__ Wih0, const float* __restrict__ Whh0,
    const float* __restrict__ bih0, const float* __restrict__ bhh0,
    const float* __restrict__ Wih1, const float* __restrict__ Whh1,
    const float* __restrict__ bih1, const float* __restrict__ bhh1,
    const float* __restrict__ Wout, const float* __restrict__ bout,
    float* __restrict__ out)
{
    // x chunks: 16 el x 64 steps x 6 f32 = 6144 floats per buffer, x2, + pad
    __shared__ float lx[2 * 6144 + 128];

    const int l   = threadIdx.x;     // 0..63
    const int g   = l >> 4;          // lane group (A k-group / D row-group)
    const int m   = l & 15;          // A row (unit) / D col (element)
    const int ew0 = blockIdx.x * 16; // wave's first batch element

    // fused weight Wf(u,k) over state v = (h1[0..7] | h2[0..7]):
    //  u<8:  k<8 -> Whh0[u][k], else 0
    //  u>=8: k<8 -> Wih1[u-8][k], else Whh1[u-8][k-8]
    auto wf = [&](int u, int k) -> float {
        if (u < 8) return (k < 8) ? Whh0[u * 8 + k] : 0.0f;
        return (k < 8) ? Wih1[(u - 8) * 8 + k] : Whh1[(u - 8) * 8 + (k - 8)];
    };

    // A-frag: lane holds A[m][k], k = 4g+i.  A = -2*KSC*Wf (r-linearized)
    // A2-frag: x-projection, A2[m][k] = KSC*Wih0[m][k] (m<8, k<6) else 0
    f16x4 Af, A2f;
#pragma unroll
    for (int i = 0; i < 4; ++i) {
        int k = 4 * g + i;
        Af[i]  = (__fp16)(-2.0f * KSC * wf(m, k));
        A2f[i] = (__fp16)((m < 8 && k < INP) ? KSC * Wih0[m * INP + k] : 0.0f);
    }
    // bias acc (D layout: lane holds rows 4g+i). Use QUANTIZED A for the
    // Wf-sum so state r=0.5 (tanh=0) is an exact fixed point:
    //   KSC*(b + sum Wf) == KSC*b - 0.5*sum A_f16
    f32x4 biasv;
#pragma unroll
    for (int i = 0; i < 4; ++i) {
        int u = 4 * g + i;
        float b = (u < 8) ? (bih0[u] + bhh0[u]) : (bih1[u - 8] + bhh1[u - 8]);
        float s = 0.0f;
        for (int k = 0; k < 16; ++k)
            s += (float)(__fp16)(-2.0f * KSC * wf(u, k));
        biasv[i] = fmaf(-0.5f, s, KSC * b);
    }
    // head: o = (bout + sum Wout) - 2*sum Wout[j]*r_h2[j]; partials on g=2,3
    float wol[4], pc;
    {
        float sw = 0.0f;
        for (int jj = 0; jj < 8; ++jj) sw += Wout[jj];
#pragma unroll
        for (int i = 0; i < 4; ++i)
            wol[i] = (g >= 2) ? -2.0f * Wout[4 * (g - 2) + i] : 0.0f;
        pc = (g == 2) ? (bout[0] + sw) : 0.0f;
    }
    float* obase = out + (size_t)(ew0 + m) * TT;
    const float* xw = x + (size_t)ew0 * (TT * INP);

    // stage chunk c1 into buffer pn; LDS float L = 64*(f>>2) + 4n + (f&3)
    // (f = 6t+d within element n); slot s = 64i + lane
    auto stage = [&](int c1, int pn) {
#pragma unroll
        for (int i = 0; i < 24; ++i) {
            const int e = l & 15;
            const int q = 4 * i + (l >> 4);
            const float* src = xw + (size_t)e * (TT * INP) + c1 * 384 + q * 4;
            gl2lds16(src, &lx[pn * 6144 + i * 256]);
        }
    };

    const char* Lb = (const char*)lx;
    // per-lane read base: +16 B per element col; g==1 reads +256 (d4,d5)
    const unsigned laneoff = (unsigned)(m * 16) + ((g == 1) ? 256u : 0u);

    f16x4 bsf;                       // state frag (r, f16)
    f32x4 D2E, D2O;                  // x-projection accs (ping-pong)
    f32x4 xE1, xO1, xE2, xO2;        // x regs, read 2 steps ahead
    float swE = 0.f, swO = 0.f, pE = 0.f, pO = 0.f;   // head deferral

    // one step: consume d2use, build d2def from xc (= x(t+2)), read a later
    // x into xr, store o(t-2), advance state.
    auto STEP = [&](f32x4& d2use, f32x4& d2def, const f32x4& xc,
                    f32x4& xr, unsigned rpb, unsigned ro1, unsigned ro2,
                    bool w128, float& swv, float& pv, int ts) {
        if (w128) {
            xr = *(const f32x4*)(Lb + rpb + ro1);
        } else {
            f32x2 a  = *(const f32x2*)(Lb + rpb + ro1);
            f32x2 b2 = *(const f32x2*)(Lb + rpb + ro2);
            xr.x = a.x; xr.y = a.y; xr.z = b2.x; xr.w = b2.y;
        }
        float o = pv + swv;              // o(t-2), swizzle issued 2 steps ago
        if (g == 2) obase[ts] = o;
        unsigned lo2 = pkrtz(xc.x, xc.y);
        unsigned hi2 = (g == 1) ? 0u : pkrtz(xc.z, xc.w);
        d2def = MFMA16(A2f, mkb(lo2, hi2), biasv);      // xproj for t+1
        f32x4 D = MFMA16(Af, bsf, d2use);               // fused update
        float r0 = __builtin_amdgcn_rcpf(__builtin_amdgcn_exp2f(D[0]) + 1.0f);
        float r1 = __builtin_amdgcn_rcpf(__builtin_amdgcn_exp2f(D[1]) + 1.0f);
        float r2 = __builtin_amdgcn_rcpf(__builtin_amdgcn_exp2f(D[2]) + 1.0f);
        float r3 = __builtin_amdgcn_rcpf(__builtin_amdgcn_exp2f(D[3]) + 1.0f);
        bsf = mkb(pkrtz(r0, r1), pkrtz(r2, r3));        // lane-local repack
        float p = fmaf(wol[3], r3, fmaf(wol[2], r2,
                  fmaf(wol[1], r1, fmaf(wol[0], r0, pc))));
        swv = swz16(p);                                  // consume at t+2
        pv = p;
    };

    // ---- prologue ----
    stage(0, 0);
    asm volatile("s_waitcnt vmcnt(0)" ::: "memory");
    __builtin_amdgcn_sched_barrier(0);
    {
        f32x4 xv0 = *(const f32x4*)(Lb + laneoff + 0);       // x(0)
        f32x4 x1v;
        {
            f32x2 a  = *(const f32x2*)(Lb + laneoff + 264);  // x(1)
            f32x2 b2 = *(const f32x2*)(Lb + laneoff + 512);
            x1v.x = a.x; x1v.y = a.y; x1v.z = b2.x; x1v.w = b2.y;
        }
        xE2 = *(const f32x4*)(Lb + laneoff + 768);           // x(2)
        {
            f32x2 a  = *(const f32x2*)(Lb + laneoff + 1032); // x(3)
            f32x2 b2 = *(const f32x2*)(Lb + laneoff + 1280);
            xO2.x = a.x; xO2.y = a.y; xO2.z = b2.x; xO2.w = b2.y;
        }
        // prologue step: entry state v=0 (r=0.5 everywhere), x(0)
        unsigned lo2 = pkrtz(xv0.x, xv0.y);
        unsigned hi2 = (g == 1) ? 0u : pkrtz(xv0.z, xv0.w);
        f32x4 D2P = MFMA16(A2f, mkb(lo2, hi2), biasv);
        bsf = mkb(0x38003800u, 0x38003800u);                 // r = 0.5
        f32x4 D = MFMA16(Af, bsf, D2P);
        float r0 = __builtin_amdgcn_rcpf(__builtin_amdgcn_exp2f(D[0]) + 1.0f);
        float r1 = __builtin_amdgcn_rcpf(__builtin_amdgcn_exp2f(D[1]) + 1.0f);
        float r2 = __builtin_amdgcn_rcpf(__builtin_amdgcn_exp2f(D[2]) + 1.0f);
        float r3 = __builtin_amdgcn_rcpf(__builtin_amdgcn_exp2f(D[3]) + 1.0f);
        unsigned blo = pkrtz(r0, r1), bhi = pkrtz(r2, r3);
        if (g >= 2) { blo = 0x38003800u; bhi = 0x38003800u; } // h2(-1)=0
        bsf = mkb(blo, bhi);
        // D2E for step 0 (projects x(1))
        lo2 = pkrtz(x1v.x, x1v.y);
        hi2 = (g == 1) ? 0u : pkrtz(x1v.z, x1v.w);
        D2E = MFMA16(A2f, mkb(lo2, hi2), biasv);
    }

    // ---- main: 8 chunks x (15 normal 4-step units + 1 boundary unit) ----
    for (int c = 0; c < 8; ++c) {
        if (c < 7) stage(c + 1, (c + 1) & 1);
        const unsigned nbo = laneoff + (((c + 1) & 1) ? 24576u : 0u);
        unsigned rpj = laneoff + ((c & 1) ? 24576u : 0u);
        const int c64 = c * 64;
        for (int j = 0; j < 15; ++j) {
            const int t0 = c64 + 4 * j;
            int tsA = t0 - 2; if (tsA < 0) tsA = 0;
            int tsB = t0 - 1; if (tsB < 0) tsB = 0;
            STEP(D2E, D2O, xE2, xE1, rpj, 1536u, 0u,    true,  swE, pE, tsA);
            STEP(D2O, D2E, xO2, xO1, rpj, 1800u, 2048u, false, swO, pO, tsB);
            STEP(D2E, D2O, xE1, xE2, rpj, 2304u, 0u,    true,  swE, pE, t0);
            STEP(D2O, D2E, xO1, xO2, rpj, 2568u, 2816u, false, swO, pO, t0 + 1);
            rpj += 1536u;
        }
        // boundary unit (steps 60..63): reads come from the next buffer
        asm volatile("s_waitcnt vmcnt(0)" ::: "memory");
        __builtin_amdgcn_sched_barrier(0);
        {
            const int t0 = c64 + 60;
            STEP(D2E, D2O, xE2, xE1, nbo, 0u,    0u,    true,  swE, pE, t0 - 2);
            STEP(D2O, D2E, xO2, xO1, nbo, 264u,  512u,  false, swO, pO, t0 - 1);
            STEP(D2E, D2O, xE1, xE2, nbo, 768u,  0u,    true,  swE, pE, t0);
            STEP(D2O, D2E, xO1, xO2, nbo, 1032u, 1280u, false, swO, pO, t0 + 1);
        }
        // c==7: "next buffer" reads are stale -> feed x(512+); they only
        // contaminate h1(512) (rows 0..7 via A2), which is never used.
    }

    // ---- epilogue: flush deferred o(510), o(511) ----
    { float o = pE + swE; if (g == 2) obase[510] = o; }
    { float o = pO + swO; if (g == 2) obase[511] = o; }
}

extern "C" void kernel_launch(void* const* d_in, const int* in_sizes, int n_in,
                              void* d_out, int out_size, void* d_ws, size_t ws_size,
                              hipStream_t stream) {
    const float* x    = (const float*)d_in[0];
    const float* Wih0 = (const float*)d_in[1];
    const float* Whh0 = (const float*)d_in[2];
    const float* bih0 = (const float*)d_in[3];
    const float* bhh0 = (const float*)d_in[4];
    const float* Wih1 = (const float*)d_in[5];
    const float* Whh1 = (const float*)d_in[6];
    const float* bih1 = (const float*)d_in[7];
    const float* bhh1 = (const float*)d_in[8];
    const float* Wout = (const float*)d_in[9];
    const float* bout = (const float*)d_in[10];
    float* out = (float*)d_out;
    (void)d_ws; (void)ws_size; (void)in_sizes; (void)n_in; (void)out_size;

    // 4096 elements / 16 per wave = 256 single-wave blocks (1 per CU)
    rnn_mfma<<<256, 64, 0, stream>>>(x, Wih0, Whh0, bih0, bhh0,
                                     Wih1, Whh1, bih1, bhh1,
                                     Wout, bout, out);
}

// Round 15
// 64.827 us; speedup vs baseline: 1.1438x; 1.0929x over previous
//
#include <hip/hip_runtime.h>

// 2-layer tanh RNN, INP=6, HID=8, B=4096, T=512, + linear head to 1.
// R15 = R10 (best, 62.1us: fused both-layers step, 16 lanes/element, head in
// lower lanes' dead slots, LDS-staged x with distance-2 prefetch) with the
// recurrence chain shortened:
//  (1) tanh via odd Pade(7,6) z*P(z2)/Q(z2) + med3 clamp: ONE transcendental
//      (rcp) in the chain instead of two (exp2+rcp). |err| <= ~9e-5.
//  (2) x-projection (bias + Wih0.x) computed one step EARLY, off-chain
//      (xaC/xaN ping-pong) -> chain starts at the gather/dot.
//  (3) dot as balanced tree (8 parallel products + 3-level add) instead of
//      two 8-deep linear fma chains.

#define INP 6
#define HID 8
#define TT  512
#define CH  64                // steps per chunk
#define NCH (TT/CH)           // 8 chunks
#define EPW 4                 // elements per wave
#define CHF (CH*INP)          // 384 floats per element-chunk
#define BUFF (EPW*CHF)        // 1536 floats per LDS buffer

#define DPP_XOR1 0xB1   // quad_perm(1,0,3,2): lane ^ 1
#define DPP_XOR2 0x4E   // quad_perm(2,3,0,1): lane ^ 2
#define DPP_XOR3 0x1B   // quad_perm(3,2,1,0): lane ^ 3
#define DPP_HMIR 0x141  // row_half_mirror:    lane ^ 7  (within 16-row)
#define DPP_RMIR 0x140  // row_mirror:         lane ^ 15 (within 16-row)
#define DPP_ROR8 0x128  // row_ror:8:          lane ^ 8  (within 16-row)

template<int CTRL>
__device__ __forceinline__ float fdpp(float v) {
    return __int_as_float(__builtin_amdgcn_update_dpp(
        0, __float_as_int(v), CTRL, 0xF, 0xF, true));
}

#if defined(__HIP_DEVICE_COMPILE__) && __has_builtin(__builtin_amdgcn_fmed3f)
  #define CLAMP1(t) __builtin_amdgcn_fmed3f((t), -1.0f, 1.0f)
#else
  #define CLAMP1(t) fminf(1.0f, fmaxf(-1.0f, (t)))
#endif

// tanh via odd Pade(7,6): z*(135135+17325z^2+378z^4+z^6) /
//                           (135135+62370z^2+3150z^4+28z^6), clamped.
// One rcp in the chain; P,Q are parallel 3-fma Horners on the FMA pipe.
// Overshoots ~1.0000..1.03 for z>5 (never dips below 1) -> clamp exact.
__device__ __forceinline__ float ftanh_pade(float z) {
    float z2 = z * z;
    float P = fmaf(fmaf(z2 + 378.0f, z2, 17325.0f), z2, 135135.0f);
    float Q = fmaf(fmaf(fmaf(28.0f, z2, 3150.0f), z2, 62370.0f), z2, 135135.0f);
    float t = (z * P) * __builtin_amdgcn_rcpf(Q);
    return CLAMP1(t);
}

// async global->LDS, 16B per lane, LDS dst = uniform base + lane*16
__device__ __forceinline__ void gl2lds16(const float* g, float* l) {
    __builtin_amdgcn_global_load_lds(
        (const __attribute__((address_space(1))) void*)g,
        (__attribute__((address_space(3))) void*)l, 16, 0, 0);
}

// read one timestep's 6 floats (3 x float2) from interleaved LDS layout:
// float f of element el lives at float offset 16*(f>>2) + 4*el + (f&3);
// BASE already includes el*4 and buffer offset. F0 = t_local*6 (even).
#define PF3(dst, base, F0) do {                                                            \
    dst[0] = *reinterpret_cast<const float2*>((base) + ((((F0)+0)>>2)<<4) + (((F0)+0)&3)); \
    dst[1] = *reinterpret_cast<const float2*>((base) + ((((F0)+2)>>2)<<4) + (((F0)+2)&3)); \
    dst[2] = *reinterpret_cast<const float2*>((base) + ((((F0)+4)>>2)<<4) + (((F0)+4)&3)); \
} while (0)

// core fused step. Entry: v = (h1(t) | h2(t-1)), xaC = bias + Wx.x(t+1).
// Exit: v = (h1(t+1) | h2(t)), xaC = bias + Wx.x(t+2) (from XNXT regs).
// Captures head o(t-1) (= s, from gathered h2(t-1)) where j == (S+7)&7.
#define STEPC(S, XNXT)                                             \
  {                                                                \
    /* next step's x-projection: off-chain */                      \
    float xaN = bias;                                              \
    xaN = fmaf(wx0, XNXT[0].x, xaN);                               \
    xaN = fmaf(wx1, XNXT[0].y, xaN);                               \
    xaN = fmaf(wx2, XNXT[1].x, xaN);                               \
    xaN = fmaf(wx3, XNXT[1].y, xaN);                               \
    xaN = fmaf(wx4, XNXT[2].x, xaN);                               \
    xaN = fmaf(wx5, XNXT[2].y, xaN);                               \
    /* 15-DPP gather of the 16-lane state row */                   \
    float g7  = fdpp<DPP_HMIR>(v);                                 \
    float g8  = fdpp<DPP_ROR8>(v);                                 \
    float g15 = fdpp<DPP_RMIR>(v);                                 \
    float g1  = fdpp<DPP_XOR1>(v);                                 \
    float g2  = fdpp<DPP_XOR2>(v);                                 \
    float g3  = fdpp<DPP_XOR3>(v);                                 \
    float g4  = fdpp<DPP_XOR3>(g7);                                \
    float g5  = fdpp<DPP_XOR2>(g7);                                \
    float g6  = fdpp<DPP_XOR1>(g7);                                \
    float g9  = fdpp<DPP_XOR1>(g8);                                \
    float g10 = fdpp<DPP_XOR2>(g8);                                \
    float g11 = fdpp<DPP_XOR3>(g8);                                \
    float g12 = fdpp<DPP_XOR3>(g15);                               \
    float g13 = fdpp<DPP_XOR2>(g15);                               \
    float g14 = fdpp<DPP_XOR1>(g15);                               \
    /* main dot: tree (8 products || 3-level add) */               \
    float p0 = wg[0] * v,   p1 = wg[1] * g1;                       \
    float p2 = wg[2] * g2,  p3 = wg[3] * g3;                       \
    float p4 = wg[4] * g4,  p5 = wg[5] * g5;                       \
    float p6 = wg[6] * g6,  p7 = wg[7] * g7;                       \
    float q0 = p0 + p1, q1 = p2 + p3, q2 = p4 + p5, q3 = p6 + p7;  \
    float r0 = q0 + q1, r1 = q2 + q3;                              \
    /* sidecar dot (head in lower lanes / Wih1 in upper) */        \
    float c0 = wg[8]  * g8,  c1 = wg[9]  * g9;                     \
    float c2 = wg[10] * g10, c3 = wg[11] * g11;                    \
    float c4 = wg[12] * g12, c5 = wg[13] * g13;                    \
    float c6 = wg[14] * g14, c7 = wg[15] * g15;                    \
    float d0 = c0 + c1, d1 = c2 + c3, d2 = c4 + c5, d3 = c6 + c7;  \
    float e0 = d0 + d1, e1 = d2 + d3;                              \
    float s = e0 + e1;                                             \
    float pre = (r0 + r1) + xaC;                                   \
    float tin = fmaf(upf, s, pre);                                 \
    v = ftanh_pade(tin);                                           \
    oreg = (j == (((S) + 7) & 7)) ? s : oreg;                      \
    xaC = xaN;                                                     \
  }

// even step: prefetch the pair consumed two steps later; next x = CURB[1]
#define STEPE(S, CURB, NXTB, PB1, F1, PB2, F2, DO1, DO2)  \
  {                                                       \
    if (DO1) PF3(NXTB[0], PB1, F1);                       \
    if (DO2) PF3(NXTB[1], PB2, F2);                       \
    STEPC(S, CURB[1])                                     \
  }
// odd step: next x = other buffer's slot 0
#define STEPO(S, OTHB) { STEPC(S, OTHB[0]) }

__global__ __launch_bounds__(64) void rnn_fused(
    const float* __restrict__ x,
    const float* __restrict__ Wih0, const float* __restrict__ Whh0,
    const float* __restrict__ bih0, const float* __restrict__ bhh0,
    const float* __restrict__ Wih1, const float* __restrict__ Whh1,
    const float* __restrict__ bih1, const float* __restrict__ bhh1,
    const float* __restrict__ Wout, const float* __restrict__ bout,
    float* __restrict__ out)
{
    __shared__ float lx[2 * BUFF];   // 12 KiB, double-buffered x chunks

    const int lane = threadIdx.x;        // 0..63
    const int j    = lane & 7;           // hidden unit owned by this lane
    const int up   = (lane >> 3) & 1;    // 0: h1 row, 1: h2 row
    const int el   = lane >> 4;          // element slot (0..3)
    const int ew0  = blockIdx.x * EPW;   // wave's first batch element

    // per-lane fused weights (RAW, no prescale):
    //  lower: m<8 -> Whh0 (gathers h1); m>=8 -> Wout[j^m] (head on h2(t-1))
    //  upper: m<8 -> Whh1 (gathers h2); m>=8 -> Wih1 (gathers h1)
    float wg[16];
#pragma unroll
    for (int M = 0; M < 8; ++M)
        wg[M] = up ? Whh1[j * HID + (j ^ M)] : Whh0[j * HID + (j ^ M)];
#pragma unroll
    for (int M = 8; M < 16; ++M)
        wg[M] = up ? Wih1[j * HID + (j ^ (M & 7))] : Wout[j ^ (M & 7)];
    const float wx0 = up ? 0.0f : Wih0[j * INP + 0];
    const float wx1 = up ? 0.0f : Wih0[j * INP + 1];
    const float wx2 = up ? 0.0f : Wih0[j * INP + 2];
    const float wx3 = up ? 0.0f : Wih0[j * INP + 3];
    const float wx4 = up ? 0.0f : Wih0[j * INP + 4];
    const float wx5 = up ? 0.0f : Wih0[j * INP + 5];
    const float bias = up ? (bih1[j] + bhh1[j]) : (bih0[j] + bhh0[j]);
    const float upf  = up ? 1.0f : 0.0f;
    const float bo   = bout[0];

    const float* xw = x + (size_t)ew0 * (TT * INP);
    float* ob = out + (size_t)(ew0 + el) * TT;

    // stage chunk c1 (4 elements x 384 floats) into buffer pn, interleaved:
    // LDS f4 slot S = q*4 + e  (e = element, q = f4 index within element)
    auto stage = [&](int c1, int pn) {
#pragma unroll
        for (int i = 0; i < 6; ++i) {
            const int e = lane & 3;
            const int q = i * 16 + (lane >> 2);
            const float* src = xw + (size_t)e * (TT * INP) + c1 * CHF + q * 4;
            gl2lds16(src, &lx[pn * BUFF + i * 256]);
        }
    };

    float v = 0.0f;           // lanes 0-7: h1(t); lanes 8-15: h2(t-1)
    float oreg = 0.0f;        // lower lanes: head outputs, slot = j
    float xaC;                // bias + Wx.x(t+1) for the upcoming step
    float2 xP[2][3], xQ[2][3];   // pair buffers: 2 timesteps each

    // ---- prologue: stage chunk 0; h1(0); prime xP=[x(1),x(2)], xaC ----
    stage(0, 0);
    asm volatile("s_waitcnt vmcnt(0)" ::: "memory");
    __builtin_amdgcn_sched_barrier(0);
    {
        const float* rb = &lx[el * 4];
        float2 x0[3];
        PF3(x0, rb, 0);        // x(0)
        PF3(xP[0], rb, 6);     // x(1)
        PF3(xP[1], rb, 12);    // x(2)
        float a = fmaf(wx0, x0[0].x, bias);
        a = fmaf(wx1, x0[0].y, a);
        a = fmaf(wx2, x0[1].x, a);
        a = fmaf(wx3, x0[1].y, a);
        a = fmaf(wx4, x0[2].x, a);
        a = fmaf(wx5, x0[2].y, a);
        float t0v = ftanh_pade(a);
        v = up ? 0.0f : t0v;   // h2(-1) = 0
        // xaC for step 0 (consumes x(1))
        xaC = bias;
        xaC = fmaf(wx0, xP[0][0].x, xaC);
        xaC = fmaf(wx1, xP[0][0].y, xaC);
        xaC = fmaf(wx2, xP[0][1].x, xaC);
        xaC = fmaf(wx3, xP[0][1].y, xaC);
        xaC = fmaf(wx4, xP[0][2].x, xaC);
        xaC = fmaf(wx5, xP[0][2].y, xaC);
    }

    for (int c = 0; c < NCH; ++c) {
        const int p = c & 1;
        if (c < NCH - 1) stage(c + 1, p ^ 1);          // ~64 steps of cover
        const float* rb = &lx[p * BUFF + el * 4];
        const float* nb = &lx[(p ^ 1) * BUFF + el * 4];

        for (int sb = 0; sb < 7; ++sb) {
            const float* rp = rb + sb * 192;           // body base
            STEPE(0, xP, xQ, rp, 18, rp, 24, true, true)
            // slot 7 completed the previous 8-step block; store it
            if ((c | sb) && !up) ob[c * CH + sb * 8 - 8 + j] = oreg + bo;
            STEPO(1, xQ)
            STEPE(2, xQ, xP, rp, 30, rp, 36, true, true)
            STEPO(3, xP)
            STEPE(4, xP, xQ, rp, 42, rp, 48, true, true)
            STEPO(5, xQ)
            STEPE(6, xQ, xP, rp, 54, rp, 60, true, true)
            STEPO(7, xP)
        }
        {   // body 7: steps 56..63, crossover into next chunk's buffer
            const float* rp = rb + 7 * 192;
            STEPE(0, xP, xQ, rp, 18, rp, 24, true, true)
            if (!up) ob[c * CH + 48 + j] = oreg + bo;      // block sb=6
            STEPO(1, xQ)
            STEPE(2, xQ, xP, rp, 30, rp, 36, true, true)
            STEPO(3, xP)
            if (c < NCH - 1) {
                // next chunk staged ~56 steps ago; drain once per chunk
                asm volatile("s_waitcnt vmcnt(0)" ::: "memory");
                __builtin_amdgcn_sched_barrier(0);
                STEPE(4, xP, xQ, rp, 42, nb, 0, true, true)  // local 63, next 0
                STEPO(5, xQ)
                STEPE(6, xQ, xP, nb, 6, nb, 12, true, true)  // next 1, next 2
                STEPO(7, xP)
            } else {
                // last chunk: x beyond t=511 doesn't exist; stale regs only
                // feed xaN for steps >= 512 (never used)
                STEPE(4, xP, xQ, rp, 42, rp, 0, true, false)
                STEPO(5, xQ)
                STEPE(6, xQ, xP, rp, 0, rp, 0, false, false)
                STEPO(7, xP)
            }
        }
    }

    // ---- epilogue: head for t = 511 (slot 7), then store final block ----
    {
        float g8  = fdpp<DPP_ROR8>(v);
        float g15 = fdpp<DPP_RMIR>(v);
        float c0 = wg[8] * g8;
        float c1 = wg[9] * fdpp<DPP_XOR1>(g8);
        c0 = fmaf(wg[10], fdpp<DPP_XOR2>(g8),  c0);
        c1 = fmaf(wg[11], fdpp<DPP_XOR3>(g8),  c1);
        c0 = fmaf(wg[12], fdpp<DPP_XOR3>(g15), c0);
        c1 = fmaf(wg[13], fdpp<DPP_XOR2>(g15), c1);
        c0 = fmaf(wg[14], fdpp<DPP_XOR1>(g15), c0);
        c1 = fmaf(wg[15], g15, c1);
        float s = c0 + c1;
        oreg = (j == 7) ? s : oreg;
        if (!up) ob[TT - 8 + j] = oreg + bo;
    }
}

extern "C" void kernel_launch(void* const* d_in, const int* in_sizes, int n_in,
                              void* d_out, int out_size, void* d_ws, size_t ws_size,
                              hipStream_t stream) {
    const float* x    = (const float*)d_in[0];
    const float* Wih0 = (const float*)d_in[1];
    const float* Whh0 = (const float*)d_in[2];
    const float* bih0 = (const float*)d_in[3];
    const float* bhh0 = (const float*)d_in[4];
    const float* Wih1 = (const float*)d_in[5];
    const float* Whh1 = (const float*)d_in[6];
    const float* bih1 = (const float*)d_in[7];
    const float* bhh1 = (const float*)d_in[8];
    const float* Wout = (const float*)d_in[9];
    const float* bout = (const float*)d_in[10];
    float* out = (float*)d_out;
    (void)d_ws; (void)ws_size; (void)in_sizes; (void)n_in; (void)out_size;

    // 4096 elements / 4 per wave = 1024 single-wave blocks -> 1 wave/SIMD
    rnn_fused<<<1024, 64, 0, stream>>>(x, Wih0, Whh0, bih0, bhh0,
                                       Wih1, Whh1, bih1, bhh1,
                                       Wout, bout, out);
}

// Round 16
// 58.338 us; speedup vs baseline: 1.2710x; 1.1112x over previous
//
#include <hip/hip_runtime.h>

// 2-layer tanh RNN, INP=6, HID=8, B=4096, T=512, + linear head to 1.
// R16 = R10 (best 62.1us) with the x path FORCED into registers:
// per 4-step body, the NEXT body's 12 ds_read_b64 are issued as inline-asm
// (un-sinkable, sched_barrier-pinned), consumed after one lgkmcnt(0) at the
// next body's top (~600 cyc cover). Steps are 100% register-resident.
// Everything else (fused both-layers step, 16 lanes/element, head in lower
// lanes' dead slots, KSC prescale, chunked global_load_lds staging) = R10.

#define INP 6
#define HID 8
#define TT  512
#define CH  64                // steps per chunk
#define NCH (TT/CH)           // 8 chunks
#define EPW 4                 // elements per wave
#define CHF (CH*INP)          // 384 floats per element-chunk
#define BUFF (EPW*CHF)        // 1536 floats per LDS buffer (6144 B)

#define DPP_XOR1 0xB1   // quad_perm(1,0,3,2): lane ^ 1
#define DPP_XOR2 0x4E   // quad_perm(2,3,0,1): lane ^ 2
#define DPP_XOR3 0x1B   // quad_perm(3,2,1,0): lane ^ 3
#define DPP_HMIR 0x141  // row_half_mirror:    lane ^ 7  (within 16-row)
#define DPP_RMIR 0x140  // row_mirror:         lane ^ 15 (within 16-row)
#define DPP_ROR8 0x128  // row_ror:8:          lane ^ 8  (within 16-row)

#define KSC 2.88539008177793f   // 2 / ln(2)

template<int CTRL>
__device__ __forceinline__ float fdpp(float v) {
    return __int_as_float(__builtin_amdgcn_update_dpp(
        0, __float_as_int(v), CTRL, 0xF, 0xF, true));
}

// tanh on PRE-SCALED input (z = 2/ln2 * raw): 1 - 2/(exp2(z)+1)
__device__ __forceinline__ float ftanhs(float z) {
    float e = __builtin_amdgcn_exp2f(z);
    return fmaf(-2.0f, __builtin_amdgcn_rcpf(e + 1.0f), 1.0f);
}

// async global->LDS, 16B per lane, LDS dst = uniform base + lane*16
__device__ __forceinline__ void gl2lds16(const float* g, float* l) {
    __builtin_amdgcn_global_load_lds(
        (const __attribute__((address_space(1))) void*)g,
        (__attribute__((address_space(3))) void*)l, 16, 0, 0);
}

#define WAITLGKM  asm volatile("s_waitcnt lgkmcnt(0)" ::: "memory")
#define WAITVM    asm volatile("s_waitcnt vmcnt(0)" ::: "memory")
#define SB        __builtin_amdgcn_sched_barrier(0)

// un-sinkable LDS read: ds_read_b64 with compile-time offset literal
#define DSRO(dst, av, LIT) \
    asm volatile("ds_read_b64 %0, %1 offset:" LIT : "=v"(dst) : "v"(av));

// 12 reads for one 4-step body whose first consumed timestep tt0 = 4*kb+1
// (odd). Offsets relative to av = chunkbase + 384*kb (bytes), from the
// interleaved layout: float f of element el at byte 64*(f>>2)+16el+4*(f&3).
#define LDB_STD(B, av)            \
    DSRO(B[0],  av, "72")         \
    DSRO(B[1],  av, "128")        \
    DSRO(B[2],  av, "136")        \
    DSRO(B[3],  av, "192")        \
    DSRO(B[4],  av, "200")        \
    DSRO(B[5],  av, "256")        \
    DSRO(B[6],  av, "264")        \
    DSRO(B[7],  av, "320")        \
    DSRO(B[8],  av, "328")        \
    DSRO(B[9],  av, "384")        \
    DSRO(B[10], av, "392")        \
    DSRO(B[11], av, "448")

// split variant for body 15: timesteps 61,62,63 from current chunk (av =
// chunkbase + 384*15), timestep 64 = next chunk's x(0) from avn
#define LDB_SPLIT(B, av, avn)     \
    DSRO(B[0],  av,  "72")        \
    DSRO(B[1],  av,  "128")       \
    DSRO(B[2],  av,  "136")       \
    DSRO(B[3],  av,  "192")       \
    DSRO(B[4],  av,  "200")       \
    DSRO(B[5],  av,  "256")       \
    DSRO(B[6],  av,  "264")       \
    DSRO(B[7],  av,  "320")       \
    DSRO(B[8],  av,  "328")       \
    DSRO(B[9],  avn, "0")         \
    DSRO(B[10], avn, "8")         \
    DSRO(B[11], avn, "64")

// core fused step (R10 verbatim, x passed as 3 float2 registers).
// Entry: v = (h1(t) | h2(t-1)). Exit: v = (h1(t+1) | h2(t)).
// Captures head o(t-1) (= s in lower lanes) into oreg where j == (S+7)&7.
#define STEPC(S, X0, X1, X2)                                       \
  {                                                                \
    float g7  = fdpp<DPP_HMIR>(v);                                 \
    float g8  = fdpp<DPP_ROR8>(v);                                 \
    float g15 = fdpp<DPP_RMIR>(v);                                 \
    float a0 = fmaf(wx0, X0.x, bias);                              \
    float a1 = wx1 * X0.y;                                         \
    a0 = fmaf(wx2, X1.x, a0);                                      \
    a1 = fmaf(wx3, X1.y, a1);                                      \
    a0 = fmaf(wx4, X2.x, a0);                                      \
    a1 = fmaf(wx5, X2.y, a1);                                      \
    a0 = fmaf(wg[0], v, a0);                                       \
    a1 = fmaf(wg[1], fdpp<DPP_XOR1>(v), a1);                       \
    a0 = fmaf(wg[2], fdpp<DPP_XOR2>(v), a0);                       \
    a1 = fmaf(wg[3], fdpp<DPP_XOR3>(v), a1);                       \
    a0 = fmaf(wg[4], fdpp<DPP_XOR3>(g7), a0);                      \
    a1 = fmaf(wg[5], fdpp<DPP_XOR2>(g7), a1);                      \
    a0 = fmaf(wg[6], fdpp<DPP_XOR1>(g7), a0);                      \
    a1 = fmaf(wg[7], g7, a1);                                      \
    float c0 = wg[8] * g8;                                         \
    float c1 = wg[9] * fdpp<DPP_XOR1>(g8);                         \
    c0 = fmaf(wg[10], fdpp<DPP_XOR2>(g8),  c0);                    \
    c1 = fmaf(wg[11], fdpp<DPP_XOR3>(g8),  c1);                    \
    c0 = fmaf(wg[12], fdpp<DPP_XOR3>(g15), c0);                    \
    c1 = fmaf(wg[13], fdpp<DPP_XOR2>(g15), c1);                    \
    c0 = fmaf(wg[14], fdpp<DPP_XOR1>(g15), c0);                    \
    c1 = fmaf(wg[15], g15, c1);                                    \
    float s   = c0 + c1;                                           \
    float pre = a0 + a1;                                           \
    float tin = fmaf(upf, s, pre);                                 \
    v = ftanhs(tin);                                               \
    oreg = (j == (((S) + 7) & 7)) ? s : oreg;                      \
  }

__global__ __launch_bounds__(64) void rnn_fused(
    const float* __restrict__ x,
    const float* __restrict__ Wih0, const float* __restrict__ Whh0,
    const float* __restrict__ bih0, const float* __restrict__ bhh0,
    const float* __restrict__ Wih1, const float* __restrict__ Whh1,
    const float* __restrict__ bih1, const float* __restrict__ bhh1,
    const float* __restrict__ Wout, const float* __restrict__ bout,
    float* __restrict__ out)
{
    __shared__ float lx[2 * BUFF];   // 12 KiB, double-buffered x chunks

    const int lane = threadIdx.x;        // 0..63
    const int j    = lane & 7;           // hidden unit owned by this lane
    const int up   = (lane >> 3) & 1;    // 0: h1 row, 1: h2 row
    const int el   = lane >> 4;          // element slot (0..3)
    const int ew0  = blockIdx.x * EPW;   // wave's first batch element

    // per-lane fused weights, tanh-path entries PRE-SCALED by 2/ln2:
    //  lower: m<8 -> K*Whh0 (gathers h1); m>=8 -> Wout[j^m] (head, UNscaled)
    //  upper: m<8 -> K*Whh1 (gathers h2); m>=8 -> K*Wih1 (gathers h1)
    float wg[16];
#pragma unroll
    for (int M = 0; M < 8; ++M)
        wg[M] = KSC * (up ? Whh1[j * HID + (j ^ M)] : Whh0[j * HID + (j ^ M)]);
#pragma unroll
    for (int M = 8; M < 16; ++M)
        wg[M] = up ? KSC * Wih1[j * HID + (j ^ (M & 7))] : Wout[j ^ (M & 7)];
    const float wx0 = up ? 0.0f : KSC * Wih0[j * INP + 0];
    const float wx1 = up ? 0.0f : KSC * Wih0[j * INP + 1];
    const float wx2 = up ? 0.0f : KSC * Wih0[j * INP + 2];
    const float wx3 = up ? 0.0f : KSC * Wih0[j * INP + 3];
    const float wx4 = up ? 0.0f : KSC * Wih0[j * INP + 4];
    const float wx5 = up ? 0.0f : KSC * Wih0[j * INP + 5];
    const float bias = KSC * (up ? (bih1[j] + bhh1[j]) : (bih0[j] + bhh0[j]));
    const float upf  = up ? 1.0f : 0.0f;
    const float bo   = bout[0];

    const float* xw = x + (size_t)ew0 * (TT * INP);
    float* ob = out + (size_t)(ew0 + el) * TT;

    // stage chunk c1 (4 elements x 384 floats) into buffer pn, interleaved:
    // LDS f4 slot S = q*4 + e
    auto stage = [&](int c1, int pn) {
#pragma unroll
        for (int i = 0; i < 6; ++i) {
            const int e = lane & 3;
            const int q = i * 16 + (lane >> 2);
            const float* src = xw + (size_t)e * (TT * INP) + c1 * CHF + q * 4;
            gl2lds16(src, &lx[pn * BUFF + i * 256]);
        }
    };

    // 32-bit LDS byte base for asm ds_read addressing
    const unsigned lb =
        (unsigned)(size_t)((__attribute__((address_space(3))) char*)(char*)lx);
    const unsigned elo = lb + (unsigned)(el * 16);

    float v = 0.0f;           // lanes 0-7: h1(t); lanes 8-15: h2(t-1)
    float oreg = 0.0f;        // lower lanes: head outputs, slot = j
    float2 XA[12], XB[12];    // 4-step x blocks, ping-pong, FORCED registers

    // ---- prologue: stage chunk 0; h1(0); issue body-0 reads ----
    stage(0, 0);
    WAITVM; SB;
    {
        // x(0): one-time C reads (offsets 0,8,64 bytes from elo)
        const float* rb = &lx[el * 4];
        float2 x00 = *reinterpret_cast<const float2*>(rb);
        float2 x01 = *reinterpret_cast<const float2*>(rb + 2);
        float2 x02 = *reinterpret_cast<const float2*>(rb + 16);
        // issue body-0 x reads (tt=1..4) while computing h1(0)
        unsigned av0 = elo;
        LDB_STD(XA, av0)
        SB;
        float a = fmaf(wx0, x00.x, bias);
        a = fmaf(wx1, x00.y, a);
        a = fmaf(wx2, x01.x, a);
        a = fmaf(wx3, x01.y, a);
        a = fmaf(wx4, x02.x, a);
        a = fmaf(wx5, x02.y, a);
        float t0v = ftanhs(a);
        v = up ? 0.0f : t0v;   // h2(-1) = 0
    }

    for (int c = 0; c < NCH; ++c) {
        const unsigned cb = elo + (unsigned)((c & 1) * 6144);
        const unsigned nb = elo + (unsigned)(((c + 1) & 1) * 6144);
        if (c < NCH - 1) stage(c + 1, (c + 1) & 1);   // ~64 steps of cover

        for (int m = 0; m < 7; ++m) {
            // body even (kb=2m): consume XA, issue XB for kb=2m+1
            WAITLGKM; SB;
            { unsigned av = cb + (unsigned)(384 * (2 * m + 1)); LDB_STD(XB, av) }
            SB;
            STEPC(0, XA[0], XA[1], XA[2])
            if ((c | m) && !up) ob[c * CH + m * 8 - 8 + j] = oreg + bo;
            STEPC(1, XA[3], XA[4], XA[5])
            STEPC(2, XA[6], XA[7], XA[8])
            STEPC(3, XA[9], XA[10], XA[11])
            // body odd (kb=2m+1): consume XB, issue XA for kb=2m+2
            WAITLGKM; SB;
            { unsigned av = cb + (unsigned)(384 * (2 * m + 2)); LDB_STD(XA, av) }
            SB;
            STEPC(4, XB[0], XB[1], XB[2])
            STEPC(5, XB[3], XB[4], XB[5])
            STEPC(6, XB[6], XB[7], XB[8])
            STEPC(7, XB[9], XB[10], XB[11])
        }
        // body 14 (kb=14): consume XA, issue XB for kb=15 (split: last
        // timestep comes from the next chunk's buffer -> drain staging first)
        WAITLGKM; SB;
        WAITVM; SB;
        { unsigned av = cb + (unsigned)(384 * 15); LDB_SPLIT(XB, av, nb) }
        SB;
        STEPC(0, XA[0], XA[1], XA[2])
        if (!up) ob[c * CH + 48 + j] = oreg + bo;     // window sb=6
        STEPC(1, XA[3], XA[4], XA[5])
        STEPC(2, XA[6], XA[7], XA[8])
        STEPC(3, XA[9], XA[10], XA[11])
        // body 15 (kb=15): consume XB, issue XA for next chunk's body 0
        WAITLGKM; SB;
        if (c < NCH - 1) { LDB_STD(XA, nb) }
        SB;
        STEPC(4, XB[0], XB[1], XB[2])
        STEPC(5, XB[3], XB[4], XB[5])
        STEPC(6, XB[6], XB[7], XB[8])
        STEPC(7, XB[9], XB[10], XB[11])
        // (c==7: XB[9..11] hold stale data -> only h1(512), never used)
    }

    // ---- epilogue: head for t = 511 (slot 7), then store final block ----
    {
        float g8  = fdpp<DPP_ROR8>(v);
        float g15 = fdpp<DPP_RMIR>(v);
        float c0 = wg[8] * g8;
        float c1 = wg[9] * fdpp<DPP_XOR1>(g8);
        c0 = fmaf(wg[10], fdpp<DPP_XOR2>(g8),  c0);
        c1 = fmaf(wg[11], fdpp<DPP_XOR3>(g8),  c1);
        c0 = fmaf(wg[12], fdpp<DPP_XOR3>(g15), c0);
        c1 = fmaf(wg[13], fdpp<DPP_XOR2>(g15), c1);
        c0 = fmaf(wg[14], fdpp<DPP_XOR1>(g15), c0);
        c1 = fmaf(wg[15], g15, c1);
        float s = c0 + c1;
        oreg = (j == 7) ? s : oreg;
        if (!up) ob[TT - 8 + j] = oreg + bo;
    }
}

extern "C" void kernel_launch(void* const* d_in, const int* in_sizes, int n_in,
                              void* d_out, int out_size, void* d_ws, size_t ws_size,
                              hipStream_t stream) {
    const float* x    = (const float*)d_in[0];
    const float* Wih0 = (const float*)d_in[1];
    const float* Whh0 = (const float*)d_in[2];
    const float* bih0 = (const float*)d_in[3];
    const float* bhh0 = (const float*)d_in[4];
    const float* Wih1 = (const float*)d_in[5];
    const float* Whh1 = (const float*)d_in[6];
    const float* bih1 = (const float*)d_in[7];
    const float* bhh1 = (const float*)d_in[8];
    const float* Wout = (const float*)d_in[9];
    const float* bout = (const float*)d_in[10];
    float* out = (float*)d_out;
    (void)d_ws; (void)ws_size; (void)in_sizes; (void)n_in; (void)out_size;

    // 4096 elements / 4 per wave = 1024 single-wave blocks -> 1 wave/SIMD
    rnn_fused<<<1024, 64, 0, stream>>>(x, Wih0, Whh0, bih0, bhh0,
                                       Wih1, Whh1, bih1, bhh1,
                                       Wout, bout, out);
}

// Round 17
// 51.280 us; speedup vs baseline: 1.4459x; 1.1376x over previous
//
#include <hip/hip_runtime.h>

// 2-layer tanh RNN, INP=6, HID=8, B=4096, T=512, + linear head to 1.
// R17 = R16 (best 58.3us) with cross-lane traffic halved:
// each 8-lane half gathers only ITS OWN state (7 DPPs) and computes the
// dot the OTHER half needs locally (lower: S1 = Wih1[j]·h1 for upper lane j;
// upper: S2 = Wout·h2 = head for lower lanes); ONE row_ror:8 DPP swaps the
// scalars across halves. 18 DPP/step -> 8. Forced inline-asm ds_read x
// pipeline, chunked global_load_lds staging, capture indexing = R16.

#define INP 6
#define HID 8
#define TT  512
#define CH  64                // steps per chunk
#define NCH (TT/CH)           // 8 chunks
#define EPW 4                 // elements per wave
#define CHF (CH*INP)          // 384 floats per element-chunk
#define BUFF (EPW*CHF)        // 1536 floats per LDS buffer (6144 B)

#define DPP_XOR1 0xB1   // quad_perm(1,0,3,2): lane ^ 1
#define DPP_XOR2 0x4E   // quad_perm(2,3,0,1): lane ^ 2
#define DPP_XOR3 0x1B   // quad_perm(3,2,1,0): lane ^ 3
#define DPP_HMIR 0x141  // row_half_mirror:    lane ^ 7 (within 8)
#define DPP_ROR8 0x128  // row_ror:8:          swap 8-lane halves in 16-row

#define KSC 2.88539008177793f   // 2 / ln(2)

template<int CTRL>
__device__ __forceinline__ float fdpp(float v) {
    return __int_as_float(__builtin_amdgcn_update_dpp(
        0, __float_as_int(v), CTRL, 0xF, 0xF, true));
}

// tanh on PRE-SCALED input (z = 2/ln2 * raw): 1 - 2/(exp2(z)+1)
__device__ __forceinline__ float ftanhs(float z) {
    float e = __builtin_amdgcn_exp2f(z);
    return fmaf(-2.0f, __builtin_amdgcn_rcpf(e + 1.0f), 1.0f);
}

// async global->LDS, 16B per lane, LDS dst = uniform base + lane*16
__device__ __forceinline__ void gl2lds16(const float* g, float* l) {
    __builtin_amdgcn_global_load_lds(
        (const __attribute__((address_space(1))) void*)g,
        (__attribute__((address_space(3))) void*)l, 16, 0, 0);
}

#define WAITLGKM  asm volatile("s_waitcnt lgkmcnt(0)" ::: "memory")
#define WAITVM    asm volatile("s_waitcnt vmcnt(0)" ::: "memory")
#define SB        __builtin_amdgcn_sched_barrier(0)

// un-sinkable LDS read: ds_read_b64 with compile-time offset literal
#define DSRO(dst, av, LIT) \
    asm volatile("ds_read_b64 %0, %1 offset:" LIT : "=v"(dst) : "v"(av));

// 12 reads for one 4-step body whose first consumed timestep tt0 = 4*kb+1.
// Offsets relative to av = chunkbase + 384*kb (bytes); interleaved layout:
// float f of element el at byte 64*(f>>2)+16el+4*(f&3).
#define LDB_STD(B, av)            \
    DSRO(B[0],  av, "72")         \
    DSRO(B[1],  av, "128")        \
    DSRO(B[2],  av, "136")        \
    DSRO(B[3],  av, "192")        \
    DSRO(B[4],  av, "200")        \
    DSRO(B[5],  av, "256")        \
    DSRO(B[6],  av, "264")        \
    DSRO(B[7],  av, "320")        \
    DSRO(B[8],  av, "328")        \
    DSRO(B[9],  av, "384")        \
    DSRO(B[10], av, "392")        \
    DSRO(B[11], av, "448")

// split variant for body 15: last timestep = next chunk's x(0) from avn
#define LDB_SPLIT(B, av, avn)     \
    DSRO(B[0],  av,  "72")        \
    DSRO(B[1],  av,  "128")       \
    DSRO(B[2],  av,  "136")       \
    DSRO(B[3],  av,  "192")       \
    DSRO(B[4],  av,  "200")       \
    DSRO(B[5],  av,  "256")       \
    DSRO(B[6],  av,  "264")       \
    DSRO(B[7],  av,  "320")       \
    DSRO(B[8],  av,  "328")       \
    DSRO(B[9],  avn, "0")         \
    DSRO(B[10], avn, "8")         \
    DSRO(B[11], avn, "64")

// core fused step. Entry: v = (h1(t) | h2(t-1)). Exit: v = (h1(t+1) | h2(t)).
// Own-half gather (7 DPP); sidecar dot computed locally for the OTHER half;
// one ROR8 swaps the scalars. ss on lower = head o(t-1): captured where
// j == (S+7)&7 (identical timing to R16).
#define STEPC(S, X0, X1, X2)                                       \
  {                                                                \
    float g1 = fdpp<DPP_XOR1>(v);                                  \
    float g2 = fdpp<DPP_XOR2>(v);                                  \
    float g3 = fdpp<DPP_XOR3>(v);                                  \
    float g7 = fdpp<DPP_HMIR>(v);                                  \
    float g4 = fdpp<DPP_XOR3>(g7);                                 \
    float g5 = fdpp<DPP_XOR2>(g7);                                 \
    float g6 = fdpp<DPP_XOR1>(g7);                                 \
    float a0 = fmaf(wx0, X0.x, bias);                              \
    float a1 = wx1 * X0.y;                                         \
    a0 = fmaf(wx2, X1.x, a0);                                      \
    a1 = fmaf(wx3, X1.y, a1);                                      \
    a0 = fmaf(wx4, X2.x, a0);                                      \
    a1 = fmaf(wx5, X2.y, a1);                                      \
    a0 = fmaf(wg[0], v, a0);                                       \
    a1 = fmaf(wg[1], g1, a1);                                      \
    a0 = fmaf(wg[2], g2, a0);                                      \
    a1 = fmaf(wg[3], g3, a1);                                      \
    a0 = fmaf(wg[4], g4, a0);                                      \
    a1 = fmaf(wg[5], g5, a1);                                      \
    a0 = fmaf(wg[6], g6, a0);                                      \
    a1 = fmaf(wg[7], g7, a1);                                      \
    float c0 = wg[8] * v;                                          \
    float c1 = wg[9] * g1;                                         \
    c0 = fmaf(wg[10], g2, c0);                                     \
    c1 = fmaf(wg[11], g3, c1);                                     \
    c0 = fmaf(wg[12], g4, c0);                                     \
    c1 = fmaf(wg[13], g5, c1);                                     \
    c0 = fmaf(wg[14], g6, c0);                                     \
    c1 = fmaf(wg[15], g7, c1);                                     \
    float s  = c0 + c1;                                            \
    float ss = fdpp<DPP_ROR8>(s);                                  \
    float pre = a0 + a1;                                           \
    float tin = fmaf(upf, ss, pre);                                \
    v = ftanhs(tin);                                               \
    oreg = (j == (((S) + 7) & 7)) ? ss : oreg;                     \
  }

__global__ __launch_bounds__(64) void rnn_fused(
    const float* __restrict__ x,
    const float* __restrict__ Wih0, const float* __restrict__ Whh0,
    const float* __restrict__ bih0, const float* __restrict__ bhh0,
    const float* __restrict__ Wih1, const float* __restrict__ Whh1,
    const float* __restrict__ bih1, const float* __restrict__ bhh1,
    const float* __restrict__ Wout, const float* __restrict__ bout,
    float* __restrict__ out)
{
    __shared__ float lx[2 * BUFF];   // 12 KiB, double-buffered x chunks

    const int lane = threadIdx.x;        // 0..63
    const int j    = lane & 7;           // hidden unit owned by this lane
    const int up   = (lane >> 3) & 1;    // 0: h1 half, 1: h2 half
    const int el   = lane >> 4;          // element slot (0..3)
    const int ew0  = blockIdx.x * EPW;   // wave's first batch element

    // per-lane weights (tanh-path PRE-SCALED by 2/ln2):
    //  wg[0..7]  main dot:    lower K*Whh0[j][j^m],  upper K*Whh1[j][j^m]
    //  wg[8..15] sidecar dot: lower K*Wih1[j][j^m] (ships to upper lane j),
    //                         upper Wout[j^m] (head, UNscaled, ships to lower)
    float wg[16];
#pragma unroll
    for (int M = 0; M < 8; ++M)
        wg[M] = KSC * (up ? Whh1[j * HID + (j ^ M)] : Whh0[j * HID + (j ^ M)]);
#pragma unroll
    for (int M = 8; M < 16; ++M)
        wg[M] = up ? Wout[j ^ (M & 7)] : KSC * Wih1[j * HID + (j ^ (M & 7))];
    const float wx0 = up ? 0.0f : KSC * Wih0[j * INP + 0];
    const float wx1 = up ? 0.0f : KSC * Wih0[j * INP + 1];
    const float wx2 = up ? 0.0f : KSC * Wih0[j * INP + 2];
    const float wx3 = up ? 0.0f : KSC * Wih0[j * INP + 3];
    const float wx4 = up ? 0.0f : KSC * Wih0[j * INP + 4];
    const float wx5 = up ? 0.0f : KSC * Wih0[j * INP + 5];
    const float bias = KSC * (up ? (bih1[j] + bhh1[j]) : (bih0[j] + bhh0[j]));
    const float upf  = up ? 1.0f : 0.0f;
    const float bo   = bout[0];

    const float* xw = x + (size_t)ew0 * (TT * INP);
    float* ob = out + (size_t)(ew0 + el) * TT;

    // stage chunk c1 (4 elements x 384 floats) into buffer pn, interleaved:
    // LDS f4 slot S = q*4 + e
    auto stage = [&](int c1, int pn) {
#pragma unroll
        for (int i = 0; i < 6; ++i) {
            const int e = lane & 3;
            const int q = i * 16 + (lane >> 2);
            const float* src = xw + (size_t)e * (TT * INP) + c1 * CHF + q * 4;
            gl2lds16(src, &lx[pn * BUFF + i * 256]);
        }
    };

    // 32-bit LDS byte base for asm ds_read addressing
    const unsigned lb =
        (unsigned)(size_t)((__attribute__((address_space(3))) char*)(char*)lx);
    const unsigned elo = lb + (unsigned)(el * 16);

    float v = 0.0f;           // lanes 0-7: h1(t); lanes 8-15: h2(t-1)
    float oreg = 0.0f;        // lower lanes: head outputs, slot = j
    float2 XA[12], XB[12];    // 4-step x blocks, ping-pong, FORCED registers

    // ---- prologue: stage chunk 0; h1(0); issue body-0 reads ----
    stage(0, 0);
    WAITVM; SB;
    {
        const float* rb = &lx[el * 4];
        float2 x00 = *reinterpret_cast<const float2*>(rb);
        float2 x01 = *reinterpret_cast<const float2*>(rb + 2);
        float2 x02 = *reinterpret_cast<const float2*>(rb + 16);
        unsigned av0 = elo;
        LDB_STD(XA, av0)
        SB;
        float a = fmaf(wx0, x00.x, bias);
        a = fmaf(wx1, x00.y, a);
        a = fmaf(wx2, x01.x, a);
        a = fmaf(wx3, x01.y, a);
        a = fmaf(wx4, x02.x, a);
        a = fmaf(wx5, x02.y, a);
        float t0v = ftanhs(a);
        v = up ? 0.0f : t0v;   // h2(-1) = 0
    }

    for (int c = 0; c < NCH; ++c) {
        const unsigned cb = elo + (unsigned)((c & 1) * 6144);
        const unsigned nb = elo + (unsigned)(((c + 1) & 1) * 6144);
        if (c < NCH - 1) stage(c + 1, (c + 1) & 1);   // ~64 steps of cover

        for (int m = 0; m < 7; ++m) {
            // body even (kb=2m): consume XA, issue XB for kb=2m+1
            WAITLGKM; SB;
            { unsigned av = cb + (unsigned)(384 * (2 * m + 1)); LDB_STD(XB, av) }
            SB;
            STEPC(0, XA[0], XA[1], XA[2])
            if ((c | m) && !up) ob[c * CH + m * 8 - 8 + j] = oreg + bo;
            STEPC(1, XA[3], XA[4], XA[5])
            STEPC(2, XA[6], XA[7], XA[8])
            STEPC(3, XA[9], XA[10], XA[11])
            // body odd (kb=2m+1): consume XB, issue XA for kb=2m+2
            WAITLGKM; SB;
            { unsigned av = cb + (unsigned)(384 * (2 * m + 2)); LDB_STD(XA, av) }
            SB;
            STEPC(4, XB[0], XB[1], XB[2])
            STEPC(5, XB[3], XB[4], XB[5])
            STEPC(6, XB[6], XB[7], XB[8])
            STEPC(7, XB[9], XB[10], XB[11])
        }
        // body 14 (kb=14): consume XA, issue XB for kb=15 (split: last
        // timestep from the next chunk's buffer -> drain staging first)
        WAITLGKM; SB;
        WAITVM; SB;
        { unsigned av = cb + (unsigned)(384 * 15); LDB_SPLIT(XB, av, nb) }
        SB;
        STEPC(0, XA[0], XA[1], XA[2])
        if (!up) ob[c * CH + 48 + j] = oreg + bo;     // window sb=6
        STEPC(1, XA[3], XA[4], XA[5])
        STEPC(2, XA[6], XA[7], XA[8])
        STEPC(3, XA[9], XA[10], XA[11])
        // body 15 (kb=15): consume XB, issue XA for next chunk's body 0
        WAITLGKM; SB;
        if (c < NCH - 1) { LDB_STD(XA, nb) }
        SB;
        STEPC(4, XB[0], XB[1], XB[2])
        STEPC(5, XB[3], XB[4], XB[5])
        STEPC(6, XB[6], XB[7], XB[8])
        STEPC(7, XB[9], XB[10], XB[11])
        // (c==7: XB[9..11] stale -> only h1(512), never used)
    }

    // ---- epilogue: head for t = 511 (slot 7), then store final block ----
    {
        float g1 = fdpp<DPP_XOR1>(v);
        float g2 = fdpp<DPP_XOR2>(v);
        float g3 = fdpp<DPP_XOR3>(v);
        float g7 = fdpp<DPP_HMIR>(v);
        float g4 = fdpp<DPP_XOR3>(g7);
        float g5 = fdpp<DPP_XOR2>(g7);
        float g6 = fdpp<DPP_XOR1>(g7);
        float c0 = wg[8] * v;
        float c1 = wg[9] * g1;
        c0 = fmaf(wg[10], g2, c0);
        c1 = fmaf(wg[11], g3, c1);
        c0 = fmaf(wg[12], g4, c0);
        c1 = fmaf(wg[13], g5, c1);
        c0 = fmaf(wg[14], g6, c0);
        c1 = fmaf(wg[15], g7, c1);
        float s  = c0 + c1;          // upper: Wout . h2(511)
        float ss = fdpp<DPP_ROR8>(s);
        oreg = (j == 7) ? ss : oreg;
        if (!up) ob[TT - 8 + j] = oreg + bo;
    }
}

extern "C" void kernel_launch(void* const* d_in, const int* in_sizes, int n_in,
                              void* d_out, int out_size, void* d_ws, size_t ws_size,
                              hipStream_t stream) {
    const float* x    = (const float*)d_in[0];
    const float* Wih0 = (const float*)d_in[1];
    const float* Whh0 = (const float*)d_in[2];
    const float* bih0 = (const float*)d_in[3];
    const float* bhh0 = (const float*)d_in[4];
    const float* Wih1 = (const float*)d_in[5];
    const float* Whh1 = (const float*)d_in[6];
    const float* bih1 = (const float*)d_in[7];
    const float* bhh1 = (const float*)d_in[8];
    const float* Wout = (const float*)d_in[9];
    const float* bout = (const float*)d_in[10];
    float* out = (float*)d_out;
    (void)d_ws; (void)ws_size; (void)in_sizes; (void)n_in; (void)out_size;

    // 4096 elements / 4 per wave = 1024 single-wave blocks -> 1 wave/SIMD
    rnn_fused<<<1024, 64, 0, stream>>>(x, Wih0, Whh0, bih0, bhh0,
                                       Wih1, Whh1, bih1, bhh1,
                                       Wout, bout, out);
}

// Round 18
// 48.807 us; speedup vs baseline: 1.5192x; 1.0507x over previous
//
#include <hip/hip_runtime.h>

// 2-layer tanh RNN, INP=6, HID=8, B=4096, T=512, + linear head to 1.
// R18 = R17 (best 51.3us) with the dot products packed into v_pk_fma_f32:
// main dot and sidecar dot accumulate (even-m, odd-m) halves in v2f pairs;
// weights pre-paired (wg[m],wg[m+1]); gathers built directly into v2f
// subregisters; x-projection also pk (x arrives as 64-bit ds_read pairs).
// 16+6 scalar FMAs -> 11 pk ops. All else R17-verbatim: half-local sidecar
// + single ROR8 scalar swap (8 DPP/step), forced inline-asm ds_read x
// pipeline, chunked global_load_lds staging.

#define INP 6
#define HID 8
#define TT  512
#define CH  64                // steps per chunk
#define NCH (TT/CH)           // 8 chunks
#define EPW 4                 // elements per wave
#define CHF (CH*INP)          // 384 floats per element-chunk
#define BUFF (EPW*CHF)        // 1536 floats per LDS buffer (6144 B)

#define DPP_XOR1 0xB1   // quad_perm(1,0,3,2): lane ^ 1
#define DPP_XOR2 0x4E   // quad_perm(2,3,0,1): lane ^ 2
#define DPP_XOR3 0x1B   // quad_perm(3,2,1,0): lane ^ 3
#define DPP_HMIR 0x141  // row_half_mirror:    lane ^ 7 (within 8)
#define DPP_ROR8 0x128  // row_ror:8:          swap 8-lane halves in 16-row

#define KSC 2.88539008177793f   // 2 / ln(2)

typedef float v2f __attribute__((ext_vector_type(2)));

template<int CTRL>
__device__ __forceinline__ float fdpp(float v) {
    return __int_as_float(__builtin_amdgcn_update_dpp(
        0, __float_as_int(v), CTRL, 0xF, 0xF, true));
}

// tanh on PRE-SCALED input (z = 2/ln2 * raw): 1 - 2/(exp2(z)+1)
__device__ __forceinline__ float ftanhs(float z) {
    float e = __builtin_amdgcn_exp2f(z);
    return fmaf(-2.0f, __builtin_amdgcn_rcpf(e + 1.0f), 1.0f);
}

// async global->LDS, 16B per lane, LDS dst = uniform base + lane*16
__device__ __forceinline__ void gl2lds16(const float* g, float* l) {
    __builtin_amdgcn_global_load_lds(
        (const __attribute__((address_space(1))) void*)g,
        (__attribute__((address_space(3))) void*)l, 16, 0, 0);
}

#define WAITLGKM  asm volatile("s_waitcnt lgkmcnt(0)" ::: "memory")
#define WAITVM    asm volatile("s_waitcnt vmcnt(0)" ::: "memory")
#define SB        __builtin_amdgcn_sched_barrier(0)

// un-sinkable LDS read: ds_read_b64 into a v2f pair, compile-time offset
#define DSRO(dst, av, LIT) \
    asm volatile("ds_read_b64 %0, %1 offset:" LIT : "=v"(dst) : "v"(av));

// 12 reads for one 4-step body, first consumed timestep tt0 = 4*kb+1.
// Offsets from av = chunkbase + 384*kb (bytes); interleaved layout:
// float f of element el at byte 64*(f>>2)+16el+4*(f&3).
#define LDB_STD(B, av)            \
    DSRO(B[0],  av, "72")         \
    DSRO(B[1],  av, "128")        \
    DSRO(B[2],  av, "136")        \
    DSRO(B[3],  av, "192")        \
    DSRO(B[4],  av, "200")        \
    DSRO(B[5],  av, "256")        \
    DSRO(B[6],  av, "264")        \
    DSRO(B[7],  av, "320")        \
    DSRO(B[8],  av, "328")        \
    DSRO(B[9],  av, "384")        \
    DSRO(B[10], av, "392")        \
    DSRO(B[11], av, "448")

// split variant for body 15: last timestep = next chunk's x(0) from avn
#define LDB_SPLIT(B, av, avn)     \
    DSRO(B[0],  av,  "72")        \
    DSRO(B[1],  av,  "128")       \
    DSRO(B[2],  av,  "136")       \
    DSRO(B[3],  av,  "192")       \
    DSRO(B[4],  av,  "200")       \
    DSRO(B[5],  av,  "256")       \
    DSRO(B[6],  av,  "264")       \
    DSRO(B[7],  av,  "320")       \
    DSRO(B[8],  av,  "328")       \
    DSRO(B[9],  avn, "0")         \
    DSRO(B[10], avn, "8")         \
    DSRO(B[11], avn, "64")

// core fused step. Entry: v = (h1(t) | h2(t-1)). Exit: v = (h1(t+1) | h2(t)).
// Own-half gather into v2f pairs (7 DPP + 1 mov); main/x/sidecar dots as pk
// ops; one ROR8 swaps the cross-half scalars. ss on lower = head o(t-1),
// captured where j == (S+7)&7 (identical to R17).
#define STEPC(S, X0, X1, X2)                                       \
  {                                                                \
    v2f G0, G1, G2, G3;                                            \
    G0.x = v;                                                      \
    G0.y = fdpp<DPP_XOR1>(v);                                      \
    G1.x = fdpp<DPP_XOR2>(v);                                      \
    G1.y = fdpp<DPP_XOR3>(v);                                      \
    G3.y = fdpp<DPP_HMIR>(v);                                      \
    G2.x = fdpp<DPP_XOR3>(G3.y);                                   \
    G2.y = fdpp<DPP_XOR2>(G3.y);                                   \
    G3.x = fdpp<DPP_XOR1>(G3.y);                                   \
    v2f PA = wxp0 * X0;                                            \
    PA = __builtin_elementwise_fma(wxp1, X1, PA);                  \
    PA = __builtin_elementwise_fma(wxp2, X2, PA);                  \
    PA = __builtin_elementwise_fma(wmp0, G0, PA);                  \
    PA = __builtin_elementwise_fma(wmp1, G1, PA);                  \
    PA = __builtin_elementwise_fma(wmp2, G2, PA);                  \
    PA = __builtin_elementwise_fma(wmp3, G3, PA);                  \
    v2f PC = wsp0 * G0;                                            \
    PC = __builtin_elementwise_fma(wsp1, G1, PC);                  \
    PC = __builtin_elementwise_fma(wsp2, G2, PC);                  \
    PC = __builtin_elementwise_fma(wsp3, G3, PC);                  \
    float s  = PC.x + PC.y;                                        \
    float ss = fdpp<DPP_ROR8>(s);                                  \
    float pre = (PA.x + PA.y) + bias;                              \
    float tin = fmaf(upf, ss, pre);                                \
    v = ftanhs(tin);                                               \
    oreg = (j == (((S) + 7) & 7)) ? ss : oreg;                     \
  }

__global__ __launch_bounds__(64) void rnn_fused(
    const float* __restrict__ x,
    const float* __restrict__ Wih0, const float* __restrict__ Whh0,
    const float* __restrict__ bih0, const float* __restrict__ bhh0,
    const float* __restrict__ Wih1, const float* __restrict__ Whh1,
    const float* __restrict__ bih1, const float* __restrict__ bhh1,
    const float* __restrict__ Wout, const float* __restrict__ bout,
    float* __restrict__ out)
{
    __shared__ float lx[2 * BUFF];   // 12 KiB, double-buffered x chunks

    const int lane = threadIdx.x;        // 0..63
    const int j    = lane & 7;           // hidden unit owned by this lane
    const int up   = (lane >> 3) & 1;    // 0: h1 half, 1: h2 half
    const int el   = lane >> 4;          // element slot (0..3)
    const int ew0  = blockIdx.x * EPW;   // wave's first batch element

    // per-lane weights (tanh-path PRE-SCALED by 2/ln2), pre-PAIRED over m:
    //  main  (wmp):  lower K*Whh0[j][j^m],  upper K*Whh1[j][j^m]
    //  side  (wsp):  lower K*Wih1[j][j^m] (ships to upper lane j),
    //                upper Wout[j^m] (head, UNscaled, ships to lower)
    v2f wmp0, wmp1, wmp2, wmp3, wsp0, wsp1, wsp2, wsp3;
    {
        float wm[8], ws[8];
#pragma unroll
        for (int M = 0; M < 8; ++M) {
            wm[M] = KSC * (up ? Whh1[j * HID + (j ^ M)]
                              : Whh0[j * HID + (j ^ M)]);
            ws[M] = up ? Wout[j ^ M] : KSC * Wih1[j * HID + (j ^ M)];
        }
        wmp0.x = wm[0]; wmp0.y = wm[1]; wmp1.x = wm[2]; wmp1.y = wm[3];
        wmp2.x = wm[4]; wmp2.y = wm[5]; wmp3.x = wm[6]; wmp3.y = wm[7];
        wsp0.x = ws[0]; wsp0.y = ws[1]; wsp1.x = ws[2]; wsp1.y = ws[3];
        wsp2.x = ws[4]; wsp2.y = ws[5]; wsp3.x = ws[6]; wsp3.y = ws[7];
    }
    v2f wxp0, wxp1, wxp2;
    wxp0.x = up ? 0.0f : KSC * Wih0[j * INP + 0];
    wxp0.y = up ? 0.0f : KSC * Wih0[j * INP + 1];
    wxp1.x = up ? 0.0f : KSC * Wih0[j * INP + 2];
    wxp1.y = up ? 0.0f : KSC * Wih0[j * INP + 3];
    wxp2.x = up ? 0.0f : KSC * Wih0[j * INP + 4];
    wxp2.y = up ? 0.0f : KSC * Wih0[j * INP + 5];
    const float bias = KSC * (up ? (bih1[j] + bhh1[j]) : (bih0[j] + bhh0[j]));
    const float upf  = up ? 1.0f : 0.0f;
    const float bo   = bout[0];

    const float* xw = x + (size_t)ew0 * (TT * INP);
    float* ob = out + (size_t)(ew0 + el) * TT;

    // stage chunk c1 (4 elements x 384 floats) into buffer pn, interleaved:
    // LDS f4 slot S = q*4 + e
    auto stage = [&](int c1, int pn) {
#pragma unroll
        for (int i = 0; i < 6; ++i) {
            const int e = lane & 3;
            const int q = i * 16 + (lane >> 2);
            const float* src = xw + (size_t)e * (TT * INP) + c1 * CHF + q * 4;
            gl2lds16(src, &lx[pn * BUFF + i * 256]);
        }
    };

    // 32-bit LDS byte base for asm ds_read addressing
    const unsigned lb =
        (unsigned)(size_t)((__attribute__((address_space(3))) char*)(char*)lx);
    const unsigned elo = lb + (unsigned)(el * 16);

    float v = 0.0f;           // lanes 0-7: h1(t); lanes 8-15: h2(t-1)
    float oreg = 0.0f;        // lower lanes: head outputs, slot = j
    v2f XA[12], XB[12];       // 4-step x blocks, ping-pong, FORCED registers

    // ---- prologue: stage chunk 0; h1(0); issue body-0 reads ----
    stage(0, 0);
    WAITVM; SB;
    {
        const float* rb = &lx[el * 4];
        v2f x00 = *reinterpret_cast<const v2f*>(rb);
        v2f x01 = *reinterpret_cast<const v2f*>(rb + 2);
        v2f x02 = *reinterpret_cast<const v2f*>(rb + 16);
        unsigned av0 = elo;
        LDB_STD(XA, av0)
        SB;
        v2f a = wxp0 * x00;
        a = __builtin_elementwise_fma(wxp1, x01, a);
        a = __builtin_elementwise_fma(wxp2, x02, a);
        float t0v = ftanhs((a.x + a.y) + bias);
        v = up ? 0.0f : t0v;   // h2(-1) = 0
    }

    for (int c = 0; c < NCH; ++c) {
        const unsigned cb = elo + (unsigned)((c & 1) * 6144);
        const unsigned nb = elo + (unsigned)(((c + 1) & 1) * 6144);
        if (c < NCH - 1) stage(c + 1, (c + 1) & 1);   // ~64 steps of cover

        for (int m = 0; m < 7; ++m) {
            // body even (kb=2m): consume XA, issue XB for kb=2m+1
            WAITLGKM; SB;
            { unsigned av = cb + (unsigned)(384 * (2 * m + 1)); LDB_STD(XB, av) }
            SB;
            STEPC(0, XA[0], XA[1], XA[2])
            if ((c | m) && !up) ob[c * CH + m * 8 - 8 + j] = oreg + bo;
            STEPC(1, XA[3], XA[4], XA[5])
            STEPC(2, XA[6], XA[7], XA[8])
            STEPC(3, XA[9], XA[10], XA[11])
            // body odd (kb=2m+1): consume XB, issue XA for kb=2m+2
            WAITLGKM; SB;
            { unsigned av = cb + (unsigned)(384 * (2 * m + 2)); LDB_STD(XA, av) }
            SB;
            STEPC(4, XB[0], XB[1], XB[2])
            STEPC(5, XB[3], XB[4], XB[5])
            STEPC(6, XB[6], XB[7], XB[8])
            STEPC(7, XB[9], XB[10], XB[11])
        }
        // body 14 (kb=14): consume XA, issue XB for kb=15 (split: last
        // timestep from the next chunk's buffer -> drain staging first)
        WAITLGKM; SB;
        WAITVM; SB;
        { unsigned av = cb + (unsigned)(384 * 15); LDB_SPLIT(XB, av, nb) }
        SB;
        STEPC(0, XA[0], XA[1], XA[2])
        if (!up) ob[c * CH + 48 + j] = oreg + bo;     // window sb=6
        STEPC(1, XA[3], XA[4], XA[5])
        STEPC(2, XA[6], XA[7], XA[8])
        STEPC(3, XA[9], XA[10], XA[11])
        // body 15 (kb=15): consume XB, issue XA for next chunk's body 0
        WAITLGKM; SB;
        if (c < NCH - 1) { LDB_STD(XA, nb) }
        SB;
        STEPC(4, XB[0], XB[1], XB[2])
        STEPC(5, XB[3], XB[4], XB[5])
        STEPC(6, XB[6], XB[7], XB[8])
        STEPC(7, XB[9], XB[10], XB[11])
        // (c==7: XB[9..11] stale -> only h1(512), never used)
    }

    // ---- epilogue: head for t = 511 (slot 7), then store final block ----
    {
        v2f G0, G1, G2, G3;
        G0.x = v;
        G0.y = fdpp<DPP_XOR1>(v);
        G1.x = fdpp<DPP_XOR2>(v);
        G1.y = fdpp<DPP_XOR3>(v);
        G3.y = fdpp<DPP_HMIR>(v);
        G2.x = fdpp<DPP_XOR3>(G3.y);
        G2.y = fdpp<DPP_XOR2>(G3.y);
        G3.x = fdpp<DPP_XOR1>(G3.y);
        v2f PC = wsp0 * G0;
        PC = __builtin_elementwise_fma(wsp1, G1, PC);
        PC = __builtin_elementwise_fma(wsp2, G2, PC);
        PC = __builtin_elementwise_fma(wsp3, G3, PC);
        float s  = PC.x + PC.y;      // upper: Wout . h2(511)
        float ss = fdpp<DPP_ROR8>(s);
        oreg = (j == 7) ? ss : oreg;
        if (!up) ob[TT - 8 + j] = oreg + bo;
    }
}

extern "C" void kernel_launch(void* const* d_in, const int* in_sizes, int n_in,
                              void* d_out, int out_size, void* d_ws, size_t ws_size,
                              hipStream_t stream) {
    const float* x    = (const float*)d_in[0];
    const float* Wih0 = (const float*)d_in[1];
    const float* Whh0 = (const float*)d_in[2];
    const float* bih0 = (const float*)d_in[3];
    const float* bhh0 = (const float*)d_in[4];
    const float* Wih1 = (const float*)d_in[5];
    const float* Whh1 = (const float*)d_in[6];
    const float* bih1 = (const float*)d_in[7];
    const float* bhh1 = (const float*)d_in[8];
    const float* Wout = (const float*)d_in[9];
    const float* bout = (const float*)d_in[10];
    float* out = (float*)d_out;
    (void)d_ws; (void)ws_size; (void)in_sizes; (void)n_in; (void)out_size;

    // 4096 elements / 4 per wave = 1024 single-wave blocks -> 1 wave/SIMD
    rnn_fused<<<1024, 64, 0, stream>>>(x, Wih0, Whh0, bih0, bhh0,
                                       Wih1, Whh1, bih1, bhh1,
                                       Wout, bout, out);
}

// Round 19
// 48.515 us; speedup vs baseline: 1.5284x; 1.0060x over previous
//
#include <hip/hip_runtime.h>

// 2-layer tanh RNN, INP=6, HID=8, B=4096, T=512, + linear head to 1.
// R19 = R18 (best 48.8us) with:
//  (a) parity-interleaved 16-lane layout (even lane = h1[u], odd = h2[u]):
//      all 7 gathers are row_ror:2c DIRECTLY from v (single-level DPP, no
//      DPP-on-DPP hazards); cross-half scalar ship = quad_perm XOR1.
//  (b) rotation direction PROBED at init (ror:2 on lane-id) -> weight set
//      selected accordingly (direction-errata-proof, zero per-step cost).
//  (c) bias folded into the PA accumulator init (biasp = (bias,0)).
// All else R18-verbatim: pk-paired dots, half-local sidecar, forced
// inline-asm ds_read x pipeline, chunked global_load_lds staging.

#define INP 6
#define HID 8
#define TT  512
#define CH  64                // steps per chunk
#define NCH (TT/CH)           // 8 chunks
#define EPW 4                 // elements per wave
#define CHF (CH*INP)          // 384 floats per element-chunk
#define BUFF (EPW*CHF)        // 1536 floats per LDS buffer (6144 B)

#define DPP_XOR1 0xB1   // quad_perm(1,0,3,2): lane ^ 1 (parity partner)
#define ROR2  0x122     // row_ror:2
#define ROR4  0x124
#define ROR6  0x126
#define ROR8  0x128
#define ROR10 0x12A
#define ROR12 0x12C
#define ROR14 0x12E

#define KSC 2.88539008177793f   // 2 / ln(2)

typedef float v2f __attribute__((ext_vector_type(2)));

template<int CTRL>
__device__ __forceinline__ float fdpp(float v) {
    return __int_as_float(__builtin_amdgcn_update_dpp(
        0, __float_as_int(v), CTRL, 0xF, 0xF, true));
}
template<int CTRL>
__device__ __forceinline__ int idpp(int v) {
    return __builtin_amdgcn_update_dpp(0, v, CTRL, 0xF, 0xF, true);
}

// tanh on PRE-SCALED input (z = 2/ln2 * raw): 1 - 2/(exp2(z)+1)
__device__ __forceinline__ float ftanhs(float z) {
    float e = __builtin_amdgcn_exp2f(z);
    return fmaf(-2.0f, __builtin_amdgcn_rcpf(e + 1.0f), 1.0f);
}

// async global->LDS, 16B per lane, LDS dst = uniform base + lane*16
__device__ __forceinline__ void gl2lds16(const float* g, float* l) {
    __builtin_amdgcn_global_load_lds(
        (const __attribute__((address_space(1))) void*)g,
        (__attribute__((address_space(3))) void*)l, 16, 0, 0);
}

#define WAITLGKM  asm volatile("s_waitcnt lgkmcnt(0)" ::: "memory")
#define WAITVM    asm volatile("s_waitcnt vmcnt(0)" ::: "memory")
#define SB        __builtin_amdgcn_sched_barrier(0)

// un-sinkable LDS read: ds_read_b64 into a v2f pair, compile-time offset
#define DSRO(dst, av, LIT) \
    asm volatile("ds_read_b64 %0, %1 offset:" LIT : "=v"(dst) : "v"(av));

// 12 reads for one 4-step body, first consumed timestep tt0 = 4*kb+1.
// Offsets from av = chunkbase + 384*kb (bytes); interleaved layout:
// float f of element el at byte 64*(f>>2)+16el+4*(f&3).
#define LDB_STD(B, av)            \
    DSRO(B[0],  av, "72")         \
    DSRO(B[1],  av, "128")        \
    DSRO(B[2],  av, "136")        \
    DSRO(B[3],  av, "192")        \
    DSRO(B[4],  av, "200")        \
    DSRO(B[5],  av, "256")        \
    DSRO(B[6],  av, "264")        \
    DSRO(B[7],  av, "320")        \
    DSRO(B[8],  av, "328")        \
    DSRO(B[9],  av, "384")        \
    DSRO(B[10], av, "392")        \
    DSRO(B[11], av, "448")

// split variant for body 15: last timestep = next chunk's x(0) from avn
#define LDB_SPLIT(B, av, avn)     \
    DSRO(B[0],  av,  "72")        \
    DSRO(B[1],  av,  "128")       \
    DSRO(B[2],  av,  "136")       \
    DSRO(B[3],  av,  "192")       \
    DSRO(B[4],  av,  "200")       \
    DSRO(B[5],  av,  "256")       \
    DSRO(B[6],  av,  "264")       \
    DSRO(B[7],  av,  "320")       \
    DSRO(B[8],  av,  "328")       \
    DSRO(B[9],  avn, "0")         \
    DSRO(B[10], avn, "8")         \
    DSRO(B[11], avn, "64")

// core fused step. Entry: v = (h1(t)|h2(t-1)) parity-interleaved.
// Exit: v = (h1(t+1)|h2(t)). Gather = 7 single-level row_ror DPPs into v2f
// pairs; dots as pk; XOR1 ships the cross-parity scalars. ss on even lanes
// = head o(t-1), captured where u == (S+7)&7.
#define STEPC(S, X0, X1, X2)                                       \
  {                                                                \
    v2f G0, G1, G2, G3;                                            \
    G0.x = v;                                                      \
    G0.y = fdpp<ROR2>(v);                                          \
    G1.x = fdpp<ROR4>(v);                                          \
    G1.y = fdpp<ROR6>(v);                                          \
    G2.x = fdpp<ROR8>(v);                                          \
    G2.y = fdpp<ROR10>(v);                                         \
    G3.x = fdpp<ROR12>(v);                                         \
    G3.y = fdpp<ROR14>(v);                                         \
    v2f PA = __builtin_elementwise_fma(wxp0, X0, biasp);           \
    PA = __builtin_elementwise_fma(wxp1, X1, PA);                  \
    PA = __builtin_elementwise_fma(wxp2, X2, PA);                  \
    PA = __builtin_elementwise_fma(wmp0, G0, PA);                  \
    PA = __builtin_elementwise_fma(wmp1, G1, PA);                  \
    PA = __builtin_elementwise_fma(wmp2, G2, PA);                  \
    PA = __builtin_elementwise_fma(wmp3, G3, PA);                  \
    v2f PC = wsp0 * G0;                                            \
    PC = __builtin_elementwise_fma(wsp1, G1, PC);                  \
    PC = __builtin_elementwise_fma(wsp2, G2, PC);                  \
    PC = __builtin_elementwise_fma(wsp3, G3, PC);                  \
    float s  = PC.x + PC.y;                                        \
    float ss = fdpp<DPP_XOR1>(s);                                  \
    float pre = PA.x + PA.y;                                       \
    float tin = fmaf(upf, ss, pre);                                \
    v = ftanhs(tin);                                               \
    oreg = (u == (((S) + 7) & 7)) ? ss : oreg;                     \
  }

__global__ __launch_bounds__(64) void rnn_fused(
    const float* __restrict__ x,
    const float* __restrict__ Wih0, const float* __restrict__ Whh0,
    const float* __restrict__ bih0, const float* __restrict__ bhh0,
    const float* __restrict__ Wih1, const float* __restrict__ Whh1,
    const float* __restrict__ bih1, const float* __restrict__ bhh1,
    const float* __restrict__ Wout, const float* __restrict__ bout,
    float* __restrict__ out)
{
    __shared__ float lx[2 * BUFF];   // 12 KiB, double-buffered x chunks

    const int lane = threadIdx.x;        // 0..63
    const int p    = lane & 1;           // 0: h1 lane, 1: h2 lane
    const int u    = (lane >> 1) & 7;    // hidden unit owned by this lane
    const int el   = lane >> 4;          // element slot (0..3)
    const int ew0  = blockIdx.x * EPW;   // wave's first batch element

    // --- probe row_ror direction: g_c = ror:2c(v) gives unit (u+dc)&7 ---
    // pr2 lane i = lid16[f(i)]; if f(i)=(i+2)&15 -> dplus
    const int lid16 = lane & 15;
    const int pr2 = idpp<ROR2>(lid16);
    const bool dplus = (pr2 == ((lid16 + 2) & 15));

    // per-lane weights (tanh-path PRE-SCALED by 2/ln2), paired over c:
    // gather c: state unit idx(c) = (u +- c) & 7, same parity.
    //  main (wmp): even K*Whh0[u][idx], odd K*Whh1[u][idx]
    //  side (wsp): even K*Wih1[u][idx] (ships to odd partner),
    //              odd Wout[idx] (head, UNscaled, ships to even partner)
    v2f wmp0, wmp1, wmp2, wmp3, wsp0, wsp1, wsp2, wsp3;
    {
        float wm[8], ws[8];
#pragma unroll
        for (int c = 0; c < 8; ++c) {
            int idx = dplus ? ((u + c) & 7) : ((u - c) & 7);
            wm[c] = KSC * (p ? Whh1[u * HID + idx] : Whh0[u * HID + idx]);
            ws[c] = p ? Wout[idx] : KSC * Wih1[u * HID + idx];
        }
        wmp0.x = wm[0]; wmp0.y = wm[1]; wmp1.x = wm[2]; wmp1.y = wm[3];
        wmp2.x = wm[4]; wmp2.y = wm[5]; wmp3.x = wm[6]; wmp3.y = wm[7];
        wsp0.x = ws[0]; wsp0.y = ws[1]; wsp1.x = ws[2]; wsp1.y = ws[3];
        wsp2.x = ws[4]; wsp2.y = ws[5]; wsp3.x = ws[6]; wsp3.y = ws[7];
    }
    v2f wxp0, wxp1, wxp2;
    wxp0.x = p ? 0.0f : KSC * Wih0[u * INP + 0];
    wxp0.y = p ? 0.0f : KSC * Wih0[u * INP + 1];
    wxp1.x = p ? 0.0f : KSC * Wih0[u * INP + 2];
    wxp1.y = p ? 0.0f : KSC * Wih0[u * INP + 3];
    wxp2.x = p ? 0.0f : KSC * Wih0[u * INP + 4];
    wxp2.y = p ? 0.0f : KSC * Wih0[u * INP + 5];
    const float bias = KSC * (p ? (bih1[u] + bhh1[u]) : (bih0[u] + bhh0[u]));
    v2f biasp; biasp.x = bias; biasp.y = 0.0f;
    const float upf  = p ? 1.0f : 0.0f;
    const float bo   = bout[0];

    const float* xw = x + (size_t)ew0 * (TT * INP);
    float* ob = out + (size_t)(ew0 + el) * TT;

    // stage chunk c1 (4 elements x 384 floats) into buffer pn, interleaved:
    // LDS f4 slot S = q*4 + e
    auto stage = [&](int c1, int pn) {
#pragma unroll
        for (int i = 0; i < 6; ++i) {
            const int e = lane & 3;
            const int q = i * 16 + (lane >> 2);
            const float* src = xw + (size_t)e * (TT * INP) + c1 * CHF + q * 4;
            gl2lds16(src, &lx[pn * BUFF + i * 256]);
        }
    };

    // 32-bit LDS byte base for asm ds_read addressing
    const unsigned lb =
        (unsigned)(size_t)((__attribute__((address_space(3))) char*)(char*)lx);
    const unsigned elo = lb + (unsigned)(el * 16);

    float v = 0.0f;           // even lanes: h1[u](t); odd lanes: h2[u](t-1)
    float oreg = 0.0f;        // even lanes: head outputs, slot = u
    v2f XA[12], XB[12];       // 4-step x blocks, ping-pong, FORCED registers

    // ---- prologue: stage chunk 0; h1(0); issue body-0 reads ----
    stage(0, 0);
    WAITVM; SB;
    {
        const float* rb = &lx[el * 4];
        v2f x00 = *reinterpret_cast<const v2f*>(rb);
        v2f x01 = *reinterpret_cast<const v2f*>(rb + 2);
        v2f x02 = *reinterpret_cast<const v2f*>(rb + 16);
        unsigned av0 = elo;
        LDB_STD(XA, av0)
        SB;
        v2f a = __builtin_elementwise_fma(wxp0, x00, biasp);
        a = __builtin_elementwise_fma(wxp1, x01, a);
        a = __builtin_elementwise_fma(wxp2, x02, a);
        float t0v = ftanhs(a.x + a.y);
        v = p ? 0.0f : t0v;    // h2(-1) = 0
    }

    for (int c = 0; c < NCH; ++c) {
        const unsigned cb = elo + (unsigned)((c & 1) * 6144);
        const unsigned nb = elo + (unsigned)(((c + 1) & 1) * 6144);
        if (c < NCH - 1) stage(c + 1, (c + 1) & 1);   // ~64 steps of cover

        for (int m = 0; m < 7; ++m) {
            // body even (kb=2m): consume XA, issue XB for kb=2m+1
            WAITLGKM; SB;
            { unsigned av = cb + (unsigned)(384 * (2 * m + 1)); LDB_STD(XB, av) }
            SB;
            STEPC(0, XA[0], XA[1], XA[2])
            if ((c | m) && !p) ob[c * CH + m * 8 - 8 + u] = oreg + bo;
            STEPC(1, XA[3], XA[4], XA[5])
            STEPC(2, XA[6], XA[7], XA[8])
            STEPC(3, XA[9], XA[10], XA[11])
            // body odd (kb=2m+1): consume XB, issue XA for kb=2m+2
            WAITLGKM; SB;
            { unsigned av = cb + (unsigned)(384 * (2 * m + 2)); LDB_STD(XA, av) }
            SB;
            STEPC(4, XB[0], XB[1], XB[2])
            STEPC(5, XB[3], XB[4], XB[5])
            STEPC(6, XB[6], XB[7], XB[8])
            STEPC(7, XB[9], XB[10], XB[11])
        }
        // body 14 (kb=14): consume XA, issue XB for kb=15 (split: last
        // timestep from the next chunk's buffer -> drain staging first)
        WAITLGKM; SB;
        WAITVM; SB;
        { unsigned av = cb + (unsigned)(384 * 15); LDB_SPLIT(XB, av, nb) }
        SB;
        STEPC(0, XA[0], XA[1], XA[2])
        if (!p) ob[c * CH + 48 + u] = oreg + bo;      // window sb=6
        STEPC(1, XA[3], XA[4], XA[5])
        STEPC(2, XA[6], XA[7], XA[8])
        STEPC(3, XA[9], XA[10], XA[11])
        // body 15 (kb=15): consume XB, issue XA for next chunk's body 0
        WAITLGKM; SB;
        if (c < NCH - 1) { LDB_STD(XA, nb) }
        SB;
        STEPC(4, XB[0], XB[1], XB[2])
        STEPC(5, XB[3], XB[4], XB[5])
        STEPC(6, XB[6], XB[7], XB[8])
        STEPC(7, XB[9], XB[10], XB[11])
        // (c==7: XB[9..11] stale -> only h1(512), never used)
    }

    // ---- epilogue: head for t = 511 (slot 7), then store final block ----
    {
        v2f G0, G1, G2, G3;
        G0.x = v;
        G0.y = fdpp<ROR2>(v);
        G1.x = fdpp<ROR4>(v);
        G1.y = fdpp<ROR6>(v);
        G2.x = fdpp<ROR8>(v);
        G2.y = fdpp<ROR10>(v);
        G3.x = fdpp<ROR12>(v);
        G3.y = fdpp<ROR14>(v);
        v2f PC = wsp0 * G0;
        PC = __builtin_elementwise_fma(wsp1, G1, PC);
        PC = __builtin_elementwise_fma(wsp2, G2, PC);
        PC = __builtin_elementwise_fma(wsp3, G3, PC);
        float s  = PC.x + PC.y;      // odd lanes: Wout . h2(511)
        float ss = fdpp<DPP_XOR1>(s);
        oreg = (u == 7) ? ss : oreg;
        if (!p) ob[TT - 8 + u] = oreg + bo;
    }
}

extern "C" void kernel_launch(void* const* d_in, const int* in_sizes, int n_in,
                              void* d_out, int out_size, void* d_ws, size_t ws_size,
                              hipStream_t stream) {
    const float* x    = (const float*)d_in[0];
    const float* Wih0 = (const float*)d_in[1];
    const float* Whh0 = (const float*)d_in[2];
    const float* bih0 = (const float*)d_in[3];
    const float* bhh0 = (const float*)d_in[4];
    const float* Wih1 = (const float*)d_in[5];
    const float* Whh1 = (const float*)d_in[6];
    const float* bih1 = (const float*)d_in[7];
    const float* bhh1 = (const float*)d_in[8];
    const float* Wout = (const float*)d_in[9];
    const float* bout = (const float*)d_in[10];
    float* out = (float*)d_out;
    (void)d_ws; (void)ws_size; (void)in_sizes; (void)n_in; (void)out_size;

    // 4096 elements / 4 per wave = 1024 single-wave blocks -> 1 wave/SIMD
    rnn_fused<<<1024, 64, 0, stream>>>(x, Wih0, Whh0, bih0, bhh0,
                                       Wih1, Whh1, bih1, bhh1,
                                       Wout, bout, out);
}